// Round 2
// baseline (636.561 us; speedup 1.0000x reference)
//
#include <hip/hip_runtime.h>

typedef unsigned short u16;
typedef __bf16 bf16x8 __attribute__((ext_vector_type(8)));
typedef float f32x4 __attribute__((ext_vector_type(4)));

#define D 64
#define LPITCH 136   // 128 + 8 bf16 pad (row = 272 B, 16B-aligned)
#define SPITCH 72    // 64 + 8 bf16 pad

__device__ __forceinline__ float b2f(u16 u) {
    unsigned v = ((unsigned)u) << 16;
    float f;
    __builtin_memcpy(&f, &v, 4);
    return f;
}
__device__ __forceinline__ u16 f2b(float f) {
    unsigned u;
    __builtin_memcpy(&u, &f, 4);
    u = u + 0x7FFFu + ((u >> 16) & 1u);   // RNE
    return (u16)(u >> 16);
}
__device__ __forceinline__ bf16x8 ld_frag(const u16* p) {
    union { uint4 u; bf16x8 b; } cv;
    cv.u = *(const uint4*)p;
    return cv.b;
}

// ---------------- CSR build ----------------
__global__ __launch_bounds__(256) void deg_kernel(const int* __restrict__ dst, int E,
                                                  int* __restrict__ deg) {
    int i = blockIdx.x * 256 + threadIdx.x;
    int stride = gridDim.x * 256;
    for (; i < E; i += stride) atomicAdd(&deg[dst[i]], 1);
}

__global__ __launch_bounds__(256) void bsum_kernel(const int* __restrict__ deg, int N,
                                                   int* __restrict__ bsum) {
    __shared__ int sm[256];
    int tid = threadIdx.x;
    int g0 = blockIdx.x * 1024 + tid * 4;
    int s = 0;
#pragma unroll
    for (int j = 0; j < 4; j++) s += (g0 + j < N) ? deg[g0 + j] : 0;
    sm[tid] = s;
    __syncthreads();
    for (int off = 128; off > 0; off >>= 1) {
        if (tid < off) sm[tid] += sm[tid + off];
        __syncthreads();
    }
    if (tid == 0) bsum[blockIdx.x] = sm[0];
}

__global__ void bscan_kernel(const int* __restrict__ bsum, int NB,
                             int* __restrict__ bscan, int* __restrict__ row_ptr, int N) {
    if (threadIdx.x == 0) {
        int run = 0;
        for (int i = 0; i < NB; i++) { bscan[i] = run; run += bsum[i]; }
        row_ptr[N] = run;
    }
}

__global__ __launch_bounds__(256) void scan_kernel(const int* __restrict__ deg,
                                                   const int* __restrict__ bscan, int N,
                                                   int* __restrict__ row_ptr,
                                                   float* __restrict__ inv_deg) {
    __shared__ int sm[256];
    int tid = threadIdx.x;
    int g0 = blockIdx.x * 1024 + tid * 4;
    int d[4];
#pragma unroll
    for (int j = 0; j < 4; j++) d[j] = (g0 + j < N) ? deg[g0 + j] : 0;
    int lsum = d[0] + d[1] + d[2] + d[3];
    sm[tid] = lsum;
    __syncthreads();
    for (int off = 1; off < 256; off <<= 1) {   // Hillis-Steele inclusive scan
        int v = (tid >= off) ? sm[tid - off] : 0;
        __syncthreads();
        sm[tid] += v;
        __syncthreads();
    }
    int run = bscan[blockIdx.x] + (sm[tid] - lsum);
#pragma unroll
    for (int j = 0; j < 4; j++) {
        int idx = g0 + j;
        if (idx < N) {
            row_ptr[idx] = run;
            inv_deg[idx] = d[j] > 0 ? 1.0f / (float)d[j] : 0.0f;
            run += d[j];
        }
    }
}

__global__ __launch_bounds__(256) void fill_kernel(const int* __restrict__ src,
                                                   const int* __restrict__ dst, int E,
                                                   const int* __restrict__ row_ptr,
                                                   int* __restrict__ cnt,
                                                   int* __restrict__ col) {
    int i = blockIdx.x * 256 + threadIdx.x;
    int stride = gridDim.x * 256;
    for (; i < E; i += stride) {
        int d_ = dst[i];
        int pos = row_ptr[d_] + atomicAdd(&cnt[d_], 1);
        col[pos] = src[i];
    }
}

// ---------------- weight prep: f32 -> bf16, transposed (B^T rows for MFMA) ----------
// WtL[l][n][k]: k<64 -> w_l[l][k][n], k>=64 -> w_r[l][k-64][n]
__global__ __launch_bounds__(256) void prep_w(const float* __restrict__ wl,
                                              const float* __restrict__ wr,
                                              const float* __restrict__ wres,
                                              const float* __restrict__ wfc,
                                              u16* __restrict__ WtL,
                                              u16* __restrict__ WresT,
                                              u16* __restrict__ WfcT) {
    int tid = threadIdx.x;
    for (int idx = tid; idx < 3 * 64 * 128; idx += 256) {
        int l = idx >> 13;
        int rem = idx & 8191;
        int n = rem >> 7;
        int k = rem & 127;
        float v = (k < 64) ? wl[l * 4096 + k * 64 + n] : wr[l * 4096 + (k - 64) * 64 + n];
        WtL[idx] = f2b(v);
    }
    for (int idx = tid; idx < 4096; idx += 256) {
        int n = idx >> 6, k = idx & 63;
        WresT[idx] = f2b(wres[k * 64 + n]);
        WfcT[idx] = f2b(wfc[k * 64 + n]);
    }
}

// ---------------- f32 -> bf16 mirror of the input features ----------------
__global__ __launch_bounds__(256) void cvt_kernel(const float* __restrict__ xf,
                                                  u16* __restrict__ xb, int total4) {
    int i = blockIdx.x * 256 + threadIdx.x;
    int stride = gridDim.x * 256;
    for (; i < total4; i += stride) {
        float4 v = *(const float4*)(xf + i * 4);
        ushort4 o;
        o.x = f2b(v.x); o.y = f2b(v.y); o.z = f2b(v.z); o.w = f2b(v.w);
        *(ushort4*)(xb + i * 4) = o;
    }
}

// ---------------- mean aggregation (pull, CSR) over the bf16 mirror ----------------
__global__ __launch_bounds__(256) void agg_kernel(const u16* __restrict__ xb,
                                                  const int* __restrict__ row_ptr,
                                                  const int* __restrict__ col,
                                                  const float* __restrict__ inv_deg,
                                                  u16* __restrict__ agg, int N) {
    int node = (blockIdx.x * 256 + threadIdx.x) >> 6;   // one wave per node
    int lane = threadIdx.x & 63;
    if (node >= N) return;
    int beg = row_ptr[node], end = row_ptr[node + 1];
    float acc = 0.f;
    int e = beg;
    for (; e + 1 < end; e += 2) {   // 2x unroll: two row loads in flight
        int s0 = col[e], s1 = col[e + 1];
        acc += b2f(xb[s0 * D + lane]);
        acc += b2f(xb[s1 * D + lane]);
    }
    if (e < end) acc += b2f(xb[col[e] * D + lane]);
    agg[node * D + lane] = f2b(acc * inv_deg[node]);
}

// ---------------- fused SAGE layer: GEMM + bias + LN + ReLU + residual ----------------
// h = [agg|x_b16] @ [W_l;W_r] + b_l ; out = relu(LN(h))*g+b + residual(f32)
__global__ __launch_bounds__(256) void layer_kernel(const u16* __restrict__ agg,
                                                    const u16* __restrict__ xbin,
                                                    const float* __restrict__ xfin, // residual (f32)
                                                    const u16* __restrict__ Wt,     // [64][128] bf16
                                                    const float* __restrict__ bl,
                                                    const float* __restrict__ gam,
                                                    const float* __restrict__ bet,
                                                    const u16* __restrict__ WresT,  // [64][64] bf16
                                                    const float* __restrict__ bres,
                                                    float* __restrict__ xfout,
                                                    u16* __restrict__ xbout,
                                                    int N, int layer0) {
    __shared__ __align__(16) u16 sA[64 * LPITCH];
    __shared__ __align__(16) u16 sB[64 * LPITCH];
    __shared__ __align__(16) u16 sR[64 * SPITCH];
    int tid = threadIdx.x;
    int base = blockIdx.x * 64;

    // stage A: 64 rows x [agg(64)|x(64)] bf16, 16B vectors
#pragma unroll
    for (int i = 0; i < 4; i++) {
        int idx = i * 256 + tid;
        int r = idx >> 4, c = idx & 15;
        int node = base + r;
        uint4 v = make_uint4(0, 0, 0, 0);
        if (node < N) {
            const u16* s = (c < 8) ? (agg + node * D + c * 8) : (xbin + node * D + (c - 8) * 8);
            v = *(const uint4*)s;
        }
        *(uint4*)&sA[r * LPITCH + c * 8] = v;
    }
    // stage B (W^T rows)
#pragma unroll
    for (int i = 0; i < 4; i++) {
        int idx = i * 256 + tid;
        int r = idx >> 4, c = idx & 15;
        *(uint4*)&sB[r * LPITCH + c * 8] = *(const uint4*)(Wt + idx * 8);
    }
    if (layer0) {
#pragma unroll
        for (int i = 0; i < 2; i++) {
            int idx = i * 256 + tid;
            int r = idx >> 3, c = idx & 7;
            *(uint4*)&sR[r * SPITCH + c * 8] = *(const uint4*)(WresT + idx * 8);
        }
    }
    __syncthreads();

    int lane = tid & 63;
    int w = tid >> 6;        // wave id: rows 16w..16w+15
    int q = lane >> 4;       // quad
    int ln = lane & 15;

    f32x4 acc[4] = {{0, 0, 0, 0}, {0, 0, 0, 0}, {0, 0, 0, 0}, {0, 0, 0, 0}};
    f32x4 accr[4] = {{0, 0, 0, 0}, {0, 0, 0, 0}, {0, 0, 0, 0}, {0, 0, 0, 0}};
    const u16* aRow = &sA[(w * 16 + ln) * LPITCH];

#pragma unroll
    for (int c = 0; c < 4; c++) {       // K = 128
        bf16x8 a = ld_frag(&aRow[c * 32 + q * 8]);
#pragma unroll
        for (int t = 0; t < 4; t++) {
            bf16x8 b = ld_frag(&sB[(t * 16 + ln) * LPITCH + c * 32 + q * 8]);
            acc[t] = __builtin_amdgcn_mfma_f32_16x16x32_bf16(a, b, acc[t], 0, 0, 0);
        }
    }
    if (layer0) {                       // residual = x @ w_res (K = 64, x half of A)
#pragma unroll
        for (int c = 0; c < 2; c++) {
            bf16x8 a = ld_frag(&aRow[64 + c * 32 + q * 8]);
#pragma unroll
            for (int t = 0; t < 4; t++) {
                bf16x8 b = ld_frag(&sR[(t * 16 + ln) * SPITCH + c * 32 + q * 8]);
                accr[t] = __builtin_amdgcn_mfma_f32_16x16x32_bf16(a, b, accr[t], 0, 0, 0);
            }
        }
    }

    // epilogue: C/D layout col = 16t + ln, row(tile) = q*4 + r
    float bcol[4], gcol[4], btcol[4], brcol[4];
#pragma unroll
    for (int t = 0; t < 4; t++) {
        int colI = t * 16 + ln;
        bcol[t] = bl[colI];
        gcol[t] = gam[colI];
        btcol[t] = bet[colI];
        brcol[t] = layer0 ? bres[colI] : 0.f;
    }
#pragma unroll
    for (int t = 0; t < 4; t++)
#pragma unroll
        for (int r = 0; r < 4; r++) acc[t][r] += bcol[t];

    float ps[4], pq[4];
#pragma unroll
    for (int r = 0; r < 4; r++) {
        float s = 0, s2 = 0;
#pragma unroll
        for (int t = 0; t < 4; t++) { float h = acc[t][r]; s += h; s2 += h * h; }
        ps[r] = s; pq[r] = s2;
    }
    for (int off = 1; off < 16; off <<= 1) {   // reduce across the 16 lanes of a quad
#pragma unroll
        for (int r = 0; r < 4; r++) {
            ps[r] += __shfl_xor(ps[r], off, 64);
            pq[r] += __shfl_xor(pq[r], off, 64);
        }
    }
#pragma unroll
    for (int r = 0; r < 4; r++) {
        int nb = w * 16 + q * 4 + r;
        int node = base + nb;
        if (node >= N) continue;
        float mu = ps[r] * (1.f / 64.f);
        float var = pq[r] * (1.f / 64.f) - mu * mu;
        var = var < 0.f ? 0.f : var;
        float rstd = rsqrtf(var + 1e-5f);
#pragma unroll
        for (int t = 0; t < 4; t++) {
            int colI = t * 16 + ln;
            float hn = (acc[t][r] - mu) * rstd * gcol[t] + btcol[t];
            hn = hn > 0.f ? hn : 0.f;
            float res = layer0 ? (accr[t][r] + brcol[t]) : xfin[node * D + colI];
            float v = hn + res;
            xfout[node * D + colI] = v;
            xbout[node * D + colI] = f2b(v);
        }
    }
}

// ---------------- final fc: out(f32) = x @ w_fc + b_fc ----------------
__global__ __launch_bounds__(256) void fc_kernel(const u16* __restrict__ xbin,
                                                 const u16* __restrict__ WfcT, // [64][64] bf16
                                                 const float* __restrict__ bfc,
                                                 float* __restrict__ out, int N) {
    __shared__ __align__(16) u16 sA[64 * SPITCH];
    __shared__ __align__(16) u16 sB[64 * SPITCH];
    int tid = threadIdx.x;
    int base = blockIdx.x * 64;
#pragma unroll
    for (int i = 0; i < 2; i++) {
        int idx = i * 256 + tid;
        int r = idx >> 3, c = idx & 7;
        int node = base + r;
        uint4 v = make_uint4(0, 0, 0, 0);
        if (node < N) v = *(const uint4*)(xbin + node * D + c * 8);
        *(uint4*)&sA[r * SPITCH + c * 8] = v;
        *(uint4*)&sB[r * SPITCH + c * 8] = *(const uint4*)(WfcT + idx * 8);
    }
    __syncthreads();
    int lane = tid & 63;
    int w = tid >> 6, q = lane >> 4, ln = lane & 15;
    f32x4 acc[4] = {{0, 0, 0, 0}, {0, 0, 0, 0}, {0, 0, 0, 0}, {0, 0, 0, 0}};
#pragma unroll
    for (int c = 0; c < 2; c++) {
        bf16x8 a = ld_frag(&sA[(w * 16 + ln) * SPITCH + c * 32 + q * 8]);
#pragma unroll
        for (int t = 0; t < 4; t++) {
            bf16x8 b = ld_frag(&sB[(t * 16 + ln) * SPITCH + c * 32 + q * 8]);
            acc[t] = __builtin_amdgcn_mfma_f32_16x16x32_bf16(a, b, acc[t], 0, 0, 0);
        }
    }
#pragma unroll
    for (int r = 0; r < 4; r++) {
        int node = base + w * 16 + q * 4 + r;
        if (node >= N) continue;
#pragma unroll
        for (int t = 0; t < 4; t++) {
            int colI = t * 16 + ln;
            out[node * D + colI] = acc[t][r] + bfc[colI];
        }
    }
}

extern "C" void kernel_launch(void* const* d_in, const int* in_sizes, int n_in,
                              void* d_out, int out_size, void* d_ws, size_t ws_size,
                              hipStream_t stream) {
    const float* x_in = (const float*)d_in[0];
    const int* e_src = (const int*)d_in[1];
    const int* e_dst = (const int*)d_in[2];
    const float* w_l = (const float*)d_in[3];
    const float* b_l = (const float*)d_in[4];
    const float* w_r = (const float*)d_in[5];
    const float* gam = (const float*)d_in[6];
    const float* bet = (const float*)d_in[7];
    const float* w_res = (const float*)d_in[8];
    const float* b_res = (const float*)d_in[9];
    const float* w_fc = (const float*)d_in[10];
    const float* b_fc = (const float*)d_in[11];
    float* out = (float*)d_out;

    const int N = in_sizes[0] / D;
    const int E = in_sizes[1];
    const int NB = (N + 1023) / 1024;

    // workspace carve-up (all offsets 256B-aligned)
    size_t o = 0;
    auto carve = [&](size_t bytes) {
        size_t cur = o;
        o += (bytes + 255) & ~(size_t)255;
        return (char*)d_ws + cur;
    };
    int* deg = (int*)carve((size_t)N * 4);
    int* cnt = (int*)carve((size_t)N * 4);
    int* row_ptr = (int*)carve((size_t)(N + 1) * 4);
    int* bsum = (int*)carve((size_t)NB * 4);
    int* bscan = (int*)carve((size_t)NB * 4);
    float* inv_deg = (float*)carve((size_t)N * 4);
    int* colA = (int*)carve((size_t)E * 4);
    u16* WtL = (u16*)carve(3 * 64 * 128 * 2);
    u16* WresT = (u16*)carve(64 * 64 * 2);
    u16* WfcT = (u16*)carve(64 * 64 * 2);
    u16* xbA = (u16*)carve((size_t)N * D * 2);    // bf16 mirror ping
    u16* xbB = (u16*)carve((size_t)N * D * 2);    // bf16 mirror pong
    u16* aggB = (u16*)carve((size_t)N * D * 2);   // bf16 aggregate
    float* xf1 = (float*)carve((size_t)N * D * 4);// f32 x after layer 0 (also L2 dump)
    float* xf2 = out;                             // f32 x after layer 1 lives in d_out

    hipMemsetAsync(deg, 0, (size_t)N * 4, stream);
    hipMemsetAsync(cnt, 0, (size_t)N * 4, stream);

    deg_kernel<<<2048, 256, 0, stream>>>(e_dst, E, deg);
    bsum_kernel<<<NB, 256, 0, stream>>>(deg, N, bsum);
    bscan_kernel<<<1, 64, 0, stream>>>(bsum, NB, bscan, row_ptr, N);
    scan_kernel<<<NB, 256, 0, stream>>>(deg, bscan, N, row_ptr, inv_deg);
    fill_kernel<<<2048, 256, 0, stream>>>(e_src, e_dst, E, row_ptr, cnt, colA);
    prep_w<<<1, 256, 0, stream>>>(w_l, w_r, w_res, w_fc, WtL, WresT, WfcT);
    cvt_kernel<<<1024, 256, 0, stream>>>(x_in, xbA, N * D / 4);

    int gridN = (N + 3) / 4;          // 4 waves/block, one wave per node
    int gridT = (N + 63) / 64;        // 64-node GEMM tiles

    // layer 0: (x_in, xbA) -> (xf1, xbB)
    agg_kernel<<<gridN, 256, 0, stream>>>(xbA, row_ptr, colA, inv_deg, aggB, N);
    layer_kernel<<<gridT, 256, 0, stream>>>(aggB, xbA, x_in, WtL, b_l, gam, bet,
                                            WresT, b_res, xf1, xbB, N, 1);
    // layer 1: (xf1, xbB) -> (xf2=d_out, xbA)
    agg_kernel<<<gridN, 256, 0, stream>>>(xbB, row_ptr, colA, inv_deg, aggB, N);
    layer_kernel<<<gridT, 256, 0, stream>>>(aggB, xbB, xf1, WtL + 8192, b_l + 64,
                                            gam + 64, bet + 64, WresT, b_res,
                                            xf2, xbA, N, 0);
    // layer 2: (xf2, xbA) -> (xf1 [discarded], xbB)
    agg_kernel<<<gridN, 256, 0, stream>>>(xbA, row_ptr, colA, inv_deg, aggB, N);
    layer_kernel<<<gridT, 256, 0, stream>>>(aggB, xbA, xf2, WtL + 16384, b_l + 128,
                                            gam + 128, bet + 128, WresT, b_res,
                                            xf1, xbB, N, 0);
    // final fc: xbB -> out (f32); overwrites xf2's scratch use of d_out
    fc_kernel<<<gridT, 256, 0, stream>>>(xbB, WfcT, b_fc, out, N);
}

// Round 3
// 527.911 us; speedup vs baseline: 1.2058x; 1.2058x over previous
//
#include <hip/hip_runtime.h>

typedef unsigned short u16;
typedef __bf16 bf16x8 __attribute__((ext_vector_type(8)));
typedef float f32x4 __attribute__((ext_vector_type(4)));

#define D 64
#define LPITCH 136   // 128 + 8 bf16 pad (row = 272 B, 16B-aligned)
#define SPITCH 72    // 64 + 8 bf16 pad

__device__ __forceinline__ float b2f(u16 u) {
    unsigned v = ((unsigned)u) << 16;
    float f;
    __builtin_memcpy(&f, &v, 4);
    return f;
}
__device__ __forceinline__ float u2f_lo(unsigned u) {   // low bf16 of a dword
    unsigned v = u << 16;
    float f;
    __builtin_memcpy(&f, &v, 4);
    return f;
}
__device__ __forceinline__ float u2f_hi(unsigned u) {   // high bf16 of a dword
    unsigned v = u & 0xFFFF0000u;
    float f;
    __builtin_memcpy(&f, &v, 4);
    return f;
}
__device__ __forceinline__ u16 f2b(float f) {
    unsigned u;
    __builtin_memcpy(&u, &f, 4);
    u = u + 0x7FFFu + ((u >> 16) & 1u);   // RNE
    return (u16)(u >> 16);
}
__device__ __forceinline__ bf16x8 ld_frag(const u16* p) {
    union { uint4 u; bf16x8 b; } cv;
    cv.u = *(const uint4*)p;
    return cv.b;
}

// ---------------- CSR build ----------------
__global__ __launch_bounds__(256) void deg_kernel(const int* __restrict__ dst, int E,
                                                  int* __restrict__ deg) {
    int i = blockIdx.x * 256 + threadIdx.x;
    int stride = gridDim.x * 256;
    int n4 = E >> 2;
    const int4* dst4 = (const int4*)dst;
    for (int j = i; j < n4; j += stride) {
        int4 d = dst4[j];
        atomicAdd(&deg[d.x], 1);
        atomicAdd(&deg[d.y], 1);
        atomicAdd(&deg[d.z], 1);
        atomicAdd(&deg[d.w], 1);
    }
    for (int j = n4 * 4 + i; j < E; j += stride) atomicAdd(&deg[dst[j]], 1);
}

__global__ __launch_bounds__(256) void bsum_kernel(const int* __restrict__ deg, int N,
                                                   int* __restrict__ bsum) {
    __shared__ int sm[256];
    int tid = threadIdx.x;
    int g0 = blockIdx.x * 1024 + tid * 4;
    int s = 0;
#pragma unroll
    for (int j = 0; j < 4; j++) s += (g0 + j < N) ? deg[g0 + j] : 0;
    sm[tid] = s;
    __syncthreads();
    for (int off = 128; off > 0; off >>= 1) {
        if (tid < off) sm[tid] += sm[tid + off];
        __syncthreads();
    }
    if (tid == 0) bsum[blockIdx.x] = sm[0];
}

__global__ void bscan_kernel(const int* __restrict__ bsum, int NB,
                             int* __restrict__ bscan, int* __restrict__ row_ptr, int N) {
    if (threadIdx.x == 0) {
        int run = 0;
        for (int i = 0; i < NB; i++) { bscan[i] = run; run += bsum[i]; }
        row_ptr[N] = run;
    }
}

__global__ __launch_bounds__(256) void scan_kernel(const int* __restrict__ deg,
                                                   const int* __restrict__ bscan, int N,
                                                   int* __restrict__ row_ptr,
                                                   float* __restrict__ inv_deg) {
    __shared__ int sm[256];
    int tid = threadIdx.x;
    int g0 = blockIdx.x * 1024 + tid * 4;
    int d[4];
#pragma unroll
    for (int j = 0; j < 4; j++) d[j] = (g0 + j < N) ? deg[g0 + j] : 0;
    int lsum = d[0] + d[1] + d[2] + d[3];
    sm[tid] = lsum;
    __syncthreads();
    for (int off = 1; off < 256; off <<= 1) {   // Hillis-Steele inclusive scan
        int v = (tid >= off) ? sm[tid - off] : 0;
        __syncthreads();
        sm[tid] += v;
        __syncthreads();
    }
    int run = bscan[blockIdx.x] + (sm[tid] - lsum);
#pragma unroll
    for (int j = 0; j < 4; j++) {
        int idx = g0 + j;
        if (idx < N) {
            row_ptr[idx] = run;
            inv_deg[idx] = d[j] > 0 ? 1.0f / (float)d[j] : 0.0f;
            run += d[j];
        }
    }
}

// fill: reuse deg[] as a countdown counter (deg is dead after scan_kernel),
// nt store on the scattered col write to curb 64B-line write amplification
__global__ __launch_bounds__(256) void fill_kernel(const int* __restrict__ src,
                                                   const int* __restrict__ dst, int E,
                                                   const int* __restrict__ row_ptr,
                                                   int* __restrict__ deg,
                                                   int* __restrict__ col) {
    int i = blockIdx.x * 256 + threadIdx.x;
    int stride = gridDim.x * 256;
    for (; i < E; i += stride) {
        int d_ = dst[i];
        int pos = row_ptr[d_] + atomicSub(&deg[d_], 1) - 1;
        __builtin_nontemporal_store(src[i], &col[pos]);
    }
}

// ---------------- weight prep: f32 -> bf16, transposed (B^T rows for MFMA) ----------
// WtL[l][n][k]: k<64 -> w_l[l][k][n], k>=64 -> w_r[l][k-64][n]
__global__ __launch_bounds__(256) void prep_w(const float* __restrict__ wl,
                                              const float* __restrict__ wr,
                                              const float* __restrict__ wres,
                                              const float* __restrict__ wfc,
                                              u16* __restrict__ WtL,
                                              u16* __restrict__ WresT,
                                              u16* __restrict__ WfcT) {
    int tid = threadIdx.x;
    for (int idx = tid; idx < 3 * 64 * 128; idx += 256) {
        int l = idx >> 13;
        int rem = idx & 8191;
        int n = rem >> 7;
        int k = rem & 127;
        float v = (k < 64) ? wl[l * 4096 + k * 64 + n] : wr[l * 4096 + (k - 64) * 64 + n];
        WtL[idx] = f2b(v);
    }
    for (int idx = tid; idx < 4096; idx += 256) {
        int n = idx >> 6, k = idx & 63;
        WresT[idx] = f2b(wres[k * 64 + n]);
        WfcT[idx] = f2b(wfc[k * 64 + n]);
    }
}

// ---------------- f32 -> bf16 mirror of the input features ----------------
__global__ __launch_bounds__(256) void cvt_kernel(const float* __restrict__ xf,
                                                  u16* __restrict__ xb, int total4) {
    int i = blockIdx.x * 256 + threadIdx.x;
    int stride = gridDim.x * 256;
    for (; i < total4; i += stride) {
        float4 v = *(const float4*)(xf + i * 4);
        ushort4 o;
        o.x = f2b(v.x); o.y = f2b(v.y); o.z = f2b(v.z); o.w = f2b(v.w);
        *(ushort4*)(xb + i * 4) = o;
    }
}

// ---------------- mean aggregation (pull, CSR), 8 edges in flight -----------------
// wave per node; lane = (edge slot = lane>>3, feature chunk = lane&7)
// each lane loads uint4 = 8 bf16 features -> one instruction gathers 8 full rows
__global__ __launch_bounds__(256) void agg_kernel(const u16* __restrict__ xb,
                                                  const int* __restrict__ row_ptr,
                                                  const int* __restrict__ col,
                                                  const float* __restrict__ inv_deg,
                                                  u16* __restrict__ agg, int N) {
    int node = (blockIdx.x * 256 + threadIdx.x) >> 6;
    int lane = threadIdx.x & 63;
    if (node >= N) return;
    int beg = row_ptr[node], end = row_ptr[node + 1];
    int slot = lane >> 3;     // which of 8 concurrent edges
    int chunk = lane & 7;     // which 8-feature chunk of the row

    float a0 = 0, a1 = 0, a2 = 0, a3 = 0, a4 = 0, a5 = 0, a6 = 0, a7 = 0;
    for (int e = beg + slot; e < end; e += 8) {
        int src = col[e];
        uint4 v = *(const uint4*)(xb + src * D + chunk * 8);
        a0 += u2f_lo(v.x); a1 += u2f_hi(v.x);
        a2 += u2f_lo(v.y); a3 += u2f_hi(v.y);
        a4 += u2f_lo(v.z); a5 += u2f_hi(v.z);
        a6 += u2f_lo(v.w); a7 += u2f_hi(v.w);
    }
    // reduce across the 8 edge slots (lanes differing in bits 3..5)
#pragma unroll
    for (int off = 8; off < 64; off <<= 1) {
        a0 += __shfl_xor(a0, off, 64);
        a1 += __shfl_xor(a1, off, 64);
        a2 += __shfl_xor(a2, off, 64);
        a3 += __shfl_xor(a3, off, 64);
        a4 += __shfl_xor(a4, off, 64);
        a5 += __shfl_xor(a5, off, 64);
        a6 += __shfl_xor(a6, off, 64);
        a7 += __shfl_xor(a7, off, 64);
    }
    if (slot == 0) {
        float m = inv_deg[node];
        uint4 o;
        o.x = (unsigned)f2b(a0 * m) | ((unsigned)f2b(a1 * m) << 16);
        o.y = (unsigned)f2b(a2 * m) | ((unsigned)f2b(a3 * m) << 16);
        o.z = (unsigned)f2b(a4 * m) | ((unsigned)f2b(a5 * m) << 16);
        o.w = (unsigned)f2b(a6 * m) | ((unsigned)f2b(a7 * m) << 16);
        *(uint4*)(agg + node * D + chunk * 8) = o;
    }
}

// ---------------- fused SAGE layer: GEMM + bias + LN + ReLU + residual ----------------
// h = [agg|x_b16] @ [W_l;W_r] + b_l ; out = relu(LN(h))*g+b + residual(f32)
__global__ __launch_bounds__(256) void layer_kernel(const u16* __restrict__ agg,
                                                    const u16* __restrict__ xbin,
                                                    const float* __restrict__ xfin, // residual (f32)
                                                    const u16* __restrict__ Wt,     // [64][128] bf16
                                                    const float* __restrict__ bl,
                                                    const float* __restrict__ gam,
                                                    const float* __restrict__ bet,
                                                    const u16* __restrict__ WresT,  // [64][64] bf16
                                                    const float* __restrict__ bres,
                                                    float* __restrict__ xfout,
                                                    u16* __restrict__ xbout,
                                                    int N, int layer0) {
    __shared__ __align__(16) u16 sA[64 * LPITCH];
    __shared__ __align__(16) u16 sB[64 * LPITCH];
    __shared__ __align__(16) u16 sR[64 * SPITCH];
    int tid = threadIdx.x;
    int base = blockIdx.x * 64;

    // stage A: 64 rows x [agg(64)|x(64)] bf16, 16B vectors
#pragma unroll
    for (int i = 0; i < 4; i++) {
        int idx = i * 256 + tid;
        int r = idx >> 4, c = idx & 15;
        int node = base + r;
        uint4 v = make_uint4(0, 0, 0, 0);
        if (node < N) {
            const u16* s = (c < 8) ? (agg + node * D + c * 8) : (xbin + node * D + (c - 8) * 8);
            v = *(const uint4*)s;
        }
        *(uint4*)&sA[r * LPITCH + c * 8] = v;
    }
    // stage B (W^T rows)
#pragma unroll
    for (int i = 0; i < 4; i++) {
        int idx = i * 256 + tid;
        int r = idx >> 4, c = idx & 15;
        *(uint4*)&sB[r * LPITCH + c * 8] = *(const uint4*)(Wt + idx * 8);
    }
    if (layer0) {
#pragma unroll
        for (int i = 0; i < 2; i++) {
            int idx = i * 256 + tid;
            int r = idx >> 3, c = idx & 7;
            *(uint4*)&sR[r * SPITCH + c * 8] = *(const uint4*)(WresT + idx * 8);
        }
    }
    __syncthreads();

    int lane = tid & 63;
    int w = tid >> 6;        // wave id: rows 16w..16w+15
    int q = lane >> 4;       // quad
    int ln = lane & 15;

    f32x4 acc[4] = {{0, 0, 0, 0}, {0, 0, 0, 0}, {0, 0, 0, 0}, {0, 0, 0, 0}};
    f32x4 accr[4] = {{0, 0, 0, 0}, {0, 0, 0, 0}, {0, 0, 0, 0}, {0, 0, 0, 0}};
    const u16* aRow = &sA[(w * 16 + ln) * LPITCH];

#pragma unroll
    for (int c = 0; c < 4; c++) {       // K = 128
        bf16x8 a = ld_frag(&aRow[c * 32 + q * 8]);
#pragma unroll
        for (int t = 0; t < 4; t++) {
            bf16x8 b = ld_frag(&sB[(t * 16 + ln) * LPITCH + c * 32 + q * 8]);
            acc[t] = __builtin_amdgcn_mfma_f32_16x16x32_bf16(a, b, acc[t], 0, 0, 0);
        }
    }
    if (layer0) {                       // residual = x @ w_res (K = 64, x half of A)
#pragma unroll
        for (int c = 0; c < 2; c++) {
            bf16x8 a = ld_frag(&aRow[64 + c * 32 + q * 8]);
#pragma unroll
            for (int t = 0; t < 4; t++) {
                bf16x8 b = ld_frag(&sR[(t * 16 + ln) * SPITCH + c * 32 + q * 8]);
                accr[t] = __builtin_amdgcn_mfma_f32_16x16x32_bf16(a, b, accr[t], 0, 0, 0);
            }
        }
    }

    // epilogue: C/D layout col = 16t + ln, row(tile) = q*4 + r
    float bcol[4], gcol[4], btcol[4], brcol[4];
#pragma unroll
    for (int t = 0; t < 4; t++) {
        int colI = t * 16 + ln;
        bcol[t] = bl[colI];
        gcol[t] = gam[colI];
        btcol[t] = bet[colI];
        brcol[t] = layer0 ? bres[colI] : 0.f;
    }
#pragma unroll
    for (int t = 0; t < 4; t++)
#pragma unroll
        for (int r = 0; r < 4; r++) acc[t][r] += bcol[t];

    float ps[4], pq[4];
#pragma unroll
    for (int r = 0; r < 4; r++) {
        float s = 0, s2 = 0;
#pragma unroll
        for (int t = 0; t < 4; t++) { float h = acc[t][r]; s += h; s2 += h * h; }
        ps[r] = s; pq[r] = s2;
    }
    for (int off = 1; off < 16; off <<= 1) {   // reduce across the 16 lanes of a quad
#pragma unroll
        for (int r = 0; r < 4; r++) {
            ps[r] += __shfl_xor(ps[r], off, 64);
            pq[r] += __shfl_xor(pq[r], off, 64);
        }
    }
#pragma unroll
    for (int r = 0; r < 4; r++) {
        int nb = w * 16 + q * 4 + r;
        int node = base + nb;
        if (node >= N) continue;
        float mu = ps[r] * (1.f / 64.f);
        float var = pq[r] * (1.f / 64.f) - mu * mu;
        var = var < 0.f ? 0.f : var;
        float rstd = rsqrtf(var + 1e-5f);
#pragma unroll
        for (int t = 0; t < 4; t++) {
            int colI = t * 16 + ln;
            float hn = (acc[t][r] - mu) * rstd * gcol[t] + btcol[t];
            hn = hn > 0.f ? hn : 0.f;
            float res = layer0 ? (accr[t][r] + brcol[t]) : xfin[node * D + colI];
            float v = hn + res;
            xfout[node * D + colI] = v;
            xbout[node * D + colI] = f2b(v);
        }
    }
}

// ---------------- final fc: out(f32) = x @ w_fc + b_fc ----------------
__global__ __launch_bounds__(256) void fc_kernel(const u16* __restrict__ xbin,
                                                 const u16* __restrict__ WfcT, // [64][64] bf16
                                                 const float* __restrict__ bfc,
                                                 float* __restrict__ out, int N) {
    __shared__ __align__(16) u16 sA[64 * SPITCH];
    __shared__ __align__(16) u16 sB[64 * SPITCH];
    int tid = threadIdx.x;
    int base = blockIdx.x * 64;
#pragma unroll
    for (int i = 0; i < 2; i++) {
        int idx = i * 256 + tid;
        int r = idx >> 3, c = idx & 7;
        int node = base + r;
        uint4 v = make_uint4(0, 0, 0, 0);
        if (node < N) v = *(const uint4*)(xbin + node * D + c * 8);
        *(uint4*)&sA[r * SPITCH + c * 8] = v;
        *(uint4*)&sB[r * SPITCH + c * 8] = *(const uint4*)(WfcT + idx * 8);
    }
    __syncthreads();
    int lane = tid & 63;
    int w = tid >> 6, q = lane >> 4, ln = lane & 15;
    f32x4 acc[4] = {{0, 0, 0, 0}, {0, 0, 0, 0}, {0, 0, 0, 0}, {0, 0, 0, 0}};
#pragma unroll
    for (int c = 0; c < 2; c++) {
        bf16x8 a = ld_frag(&sA[(w * 16 + ln) * SPITCH + c * 32 + q * 8]);
#pragma unroll
        for (int t = 0; t < 4; t++) {
            bf16x8 b = ld_frag(&sB[(t * 16 + ln) * SPITCH + c * 32 + q * 8]);
            acc[t] = __builtin_amdgcn_mfma_f32_16x16x32_bf16(a, b, acc[t], 0, 0, 0);
        }
    }
#pragma unroll
    for (int r = 0; r < 4; r++) {
        int node = base + w * 16 + q * 4 + r;
        if (node >= N) continue;
#pragma unroll
        for (int t = 0; t < 4; t++) {
            int colI = t * 16 + ln;
            out[node * D + colI] = acc[t][r] + bfc[colI];
        }
    }
}

extern "C" void kernel_launch(void* const* d_in, const int* in_sizes, int n_in,
                              void* d_out, int out_size, void* d_ws, size_t ws_size,
                              hipStream_t stream) {
    const float* x_in = (const float*)d_in[0];
    const int* e_src = (const int*)d_in[1];
    const int* e_dst = (const int*)d_in[2];
    const float* w_l = (const float*)d_in[3];
    const float* b_l = (const float*)d_in[4];
    const float* w_r = (const float*)d_in[5];
    const float* gam = (const float*)d_in[6];
    const float* bet = (const float*)d_in[7];
    const float* w_res = (const float*)d_in[8];
    const float* b_res = (const float*)d_in[9];
    const float* w_fc = (const float*)d_in[10];
    const float* b_fc = (const float*)d_in[11];
    float* out = (float*)d_out;

    const int N = in_sizes[0] / D;
    const int E = in_sizes[1];
    const int NB = (N + 1023) / 1024;

    // workspace carve-up (all offsets 256B-aligned)
    size_t o = 0;
    auto carve = [&](size_t bytes) {
        size_t cur = o;
        o += (bytes + 255) & ~(size_t)255;
        return (char*)d_ws + cur;
    };
    int* deg = (int*)carve((size_t)N * 4);
    int* row_ptr = (int*)carve((size_t)(N + 1) * 4);
    int* bsum = (int*)carve((size_t)NB * 4);
    int* bscan = (int*)carve((size_t)NB * 4);
    float* inv_deg = (float*)carve((size_t)N * 4);
    int* colA = (int*)carve((size_t)E * 4);
    u16* WtL = (u16*)carve(3 * 64 * 128 * 2);
    u16* WresT = (u16*)carve(64 * 64 * 2);
    u16* WfcT = (u16*)carve(64 * 64 * 2);
    u16* xbA = (u16*)carve((size_t)N * D * 2);    // bf16 mirror ping
    u16* xbB = (u16*)carve((size_t)N * D * 2);    // bf16 mirror pong
    u16* aggB = (u16*)carve((size_t)N * D * 2);   // bf16 aggregate
    float* xf1 = (float*)carve((size_t)N * D * 4);// f32 x after layer 0
    float* xf2 = out;                             // f32 x after layer 1 lives in d_out

    hipMemsetAsync(deg, 0, (size_t)N * 4, stream);

    deg_kernel<<<2048, 256, 0, stream>>>(e_dst, E, deg);
    bsum_kernel<<<NB, 256, 0, stream>>>(deg, N, bsum);
    bscan_kernel<<<1, 64, 0, stream>>>(bsum, NB, bscan, row_ptr, N);
    scan_kernel<<<NB, 256, 0, stream>>>(deg, bscan, N, row_ptr, inv_deg);
    fill_kernel<<<2048, 256, 0, stream>>>(e_src, e_dst, E, row_ptr, deg, colA);
    prep_w<<<1, 256, 0, stream>>>(w_l, w_r, w_res, w_fc, WtL, WresT, WfcT);
    cvt_kernel<<<1024, 256, 0, stream>>>(x_in, xbA, N * D / 4);

    int gridN = (N + 3) / 4;          // 4 waves/block, one wave per node
    int gridT = (N + 63) / 64;        // 64-node GEMM tiles

    // layer 0: (x_in, xbA) -> (xf1, xbB)
    agg_kernel<<<gridN, 256, 0, stream>>>(xbA, row_ptr, colA, inv_deg, aggB, N);
    layer_kernel<<<gridT, 256, 0, stream>>>(aggB, xbA, x_in, WtL, b_l, gam, bet,
                                            WresT, b_res, xf1, xbB, N, 1);
    // layer 1: (xf1, xbB) -> (xf2=d_out, xbA)
    agg_kernel<<<gridN, 256, 0, stream>>>(xbB, row_ptr, colA, inv_deg, aggB, N);
    layer_kernel<<<gridT, 256, 0, stream>>>(aggB, xbB, xf1, WtL + 8192, b_l + 64,
                                            gam + 64, bet + 64, WresT, b_res,
                                            xf2, xbA, N, 0);
    // layer 2: (xf2, xbA) -> (xf1 [discarded], xbB)
    agg_kernel<<<gridN, 256, 0, stream>>>(xbA, row_ptr, colA, inv_deg, aggB, N);
    layer_kernel<<<gridT, 256, 0, stream>>>(aggB, xbA, xf2, WtL + 16384, b_l + 128,
                                            gam + 128, bet + 128, WresT, b_res,
                                            xf1, xbB, N, 0);
    // final fc: xbB -> out (f32); overwrites xf2's scratch use of d_out
    fc_kernel<<<gridT, 256, 0, stream>>>(xbB, WfcT, b_fc, out, N);
}

// Round 4
// 418.054 us; speedup vs baseline: 1.5227x; 1.2628x over previous
//
#include <hip/hip_runtime.h>

typedef unsigned short u16;
typedef __bf16 bf16x8 __attribute__((ext_vector_type(8)));
typedef float f32x4 __attribute__((ext_vector_type(4)));

#define D 64
#define LPITCH 136   // 128 + 8 bf16 pad
#define SPITCH 72    // 64 + 8 bf16 pad
#define CHUNKS 512   // edge-array partitions for binning

__device__ __forceinline__ float b2f(u16 u) {
    unsigned v = ((unsigned)u) << 16;
    float f;
    __builtin_memcpy(&f, &v, 4);
    return f;
}
__device__ __forceinline__ float u2f_lo(unsigned u) {
    unsigned v = u << 16;
    float f;
    __builtin_memcpy(&f, &v, 4);
    return f;
}
__device__ __forceinline__ float u2f_hi(unsigned u) {
    unsigned v = u & 0xFFFF0000u;
    float f;
    __builtin_memcpy(&f, &v, 4);
    return f;
}
__device__ __forceinline__ u16 f2b(float f) {
    unsigned u;
    __builtin_memcpy(&u, &f, 4);
    u = u + 0x7FFFu + ((u >> 16) & 1u);   // RNE
    return (u16)(u >> 16);
}
__device__ __forceinline__ bf16x8 ld_frag(const u16* p) {
    union { uint4 u; bf16x8 b; } cv;
    cv.u = *(const uint4*)p;
    return cv.b;
}

// ---------------- binned CSR build ----------------
// binA: per-chunk bucket histogram (LDS) + global node-degree histogram (fused deg_kernel)
__global__ __launch_bounds__(256) void binA_kernel(const int* __restrict__ dst, int E,
                                                   int* __restrict__ deg,
                                                   int* __restrict__ H,   // [CHUNKS][nbuck]
                                                   int shift, int nbuck, int eper) {
    __shared__ int hist[256];
    int t = threadIdx.x;
    int c = blockIdx.x;
    hist[t] = 0;
    __syncthreads();
    int beg = c * eper;
    int end = min(beg + eper, E);
    for (int i = beg + t; i < end; i += 256) {
        int d = dst[i];
        atomicAdd(&hist[d >> shift], 1);
        atomicAdd(&deg[d], 1);
    }
    __syncthreads();
    if (t < nbuck) H[c * nbuck + t] = hist[t];
}

// binS2: per-bucket exclusive scan of chunk counts -> absolute staging offsets O[c][b]
// bucket base in the col/staging array is row_ptr[b<<shift]
__global__ __launch_bounds__(256) void binS2_kernel(const int* __restrict__ H,
                                                    const int* __restrict__ row_ptr,
                                                    int* __restrict__ O,
                                                    int shift, int nbuck, int N) {
    __shared__ int ss[256];
    int b = blockIdx.x;
    int t = threadIdx.x;
    int h0 = H[(2 * t) * nbuck + b];
    int h1 = H[(2 * t + 1) * nbuck + b];
    ss[t] = h0 + h1;
    __syncthreads();
    for (int off = 1; off < 256; off <<= 1) {   // Hillis-Steele inclusive
        int v = (t >= off) ? ss[t - off] : 0;
        __syncthreads();
        ss[t] += v;
        __syncthreads();
    }
    int node0 = b << shift;
    int base = row_ptr[node0 < N ? node0 : N];
    int excl = ss[t] - h0 - h1;
    O[(2 * t) * nbuck + b] = base + excl;
    O[(2 * t + 1) * nbuck + b] = base + excl + h0;
}

// binB: scatter packed (src | local_dst<<17) into bucket-grouped staging
__global__ __launch_bounds__(256) void binB_kernel(const int* __restrict__ src,
                                                   const int* __restrict__ dst, int E,
                                                   const int* __restrict__ O,
                                                   int* __restrict__ staging,
                                                   int shift, int nbuck, int eper) {
    __shared__ int pos[256];
    int t = threadIdx.x;
    int c = blockIdx.x;
    if (t < nbuck) pos[t] = O[c * nbuck + t];
    __syncthreads();
    int beg = c * eper;
    int end = min(beg + eper, E);
    int mask = (1 << shift) - 1;
    for (int i = beg + t; i < end; i += 256) {
        int d = dst[i];
        int b = d >> shift;
        int p = atomicAdd(&pos[b], 1);
        staging[p] = src[i] | ((d & mask) << 17);
    }
}

// binC: block per bucket; countdown + row_ptr slices in LDS; col writes stay in a hot region
__global__ __launch_bounds__(256) void binC_kernel(const int* __restrict__ staging,
                                                   const int* __restrict__ row_ptr,
                                                   const int* __restrict__ deg,
                                                   int* __restrict__ col,
                                                   int shift, int N) {
    __shared__ int ldeg[1024];
    __shared__ int lrp[1025];
    int b = blockIdx.x;
    int t = threadIdx.x;
    int node0 = b << shift;
    int nn = min(1 << shift, N - node0);
    for (int i = t; i < nn; i += 256) {
        ldeg[i] = deg[node0 + i];
        lrp[i] = row_ptr[node0 + i];
    }
    if (t == 0) lrp[nn] = row_ptr[node0 + nn];
    __syncthreads();
    int beg = lrp[0], end = lrp[nn];
    for (int i = beg + t; i < end; i += 256) {
        int word = staging[i];
        int s = word & 0x1FFFF;
        int ld = word >> 17;
        int cnt = atomicSub(&ldeg[ld], 1) - 1;
        col[lrp[ld] + cnt] = s;
    }
}

// ---------------- row_ptr scan helpers ----------------
__global__ __launch_bounds__(256) void bsum_kernel(const int* __restrict__ deg, int N,
                                                   int* __restrict__ bsum) {
    __shared__ int sm[256];
    int tid = threadIdx.x;
    int g0 = blockIdx.x * 1024 + tid * 4;
    int s = 0;
#pragma unroll
    for (int j = 0; j < 4; j++) s += (g0 + j < N) ? deg[g0 + j] : 0;
    sm[tid] = s;
    __syncthreads();
    for (int off = 128; off > 0; off >>= 1) {
        if (tid < off) sm[tid] += sm[tid + off];
        __syncthreads();
    }
    if (tid == 0) bsum[blockIdx.x] = sm[0];
}

// parallel LDS scan over block sums (NB <= 256)
__global__ __launch_bounds__(256) void bscan_kernel(const int* __restrict__ bsum, int NB,
                                                    int* __restrict__ bscan,
                                                    int* __restrict__ row_ptr, int N) {
    __shared__ int sm[256];
    int t = threadIdx.x;
    int v = (t < NB) ? bsum[t] : 0;
    sm[t] = v;
    __syncthreads();
    for (int off = 1; off < 256; off <<= 1) {
        int u = (t >= off) ? sm[t - off] : 0;
        __syncthreads();
        sm[t] += u;
        __syncthreads();
    }
    if (t < NB) bscan[t] = sm[t] - v;       // exclusive
    if (t == 255) row_ptr[N] = sm[255];     // total edges
}

__global__ __launch_bounds__(256) void scan_kernel(const int* __restrict__ deg,
                                                   const int* __restrict__ bscan, int N,
                                                   int* __restrict__ row_ptr,
                                                   float* __restrict__ inv_deg) {
    __shared__ int sm[256];
    int tid = threadIdx.x;
    int g0 = blockIdx.x * 1024 + tid * 4;
    int d[4];
#pragma unroll
    for (int j = 0; j < 4; j++) d[j] = (g0 + j < N) ? deg[g0 + j] : 0;
    int lsum = d[0] + d[1] + d[2] + d[3];
    sm[tid] = lsum;
    __syncthreads();
    for (int off = 1; off < 256; off <<= 1) {
        int v = (tid >= off) ? sm[tid - off] : 0;
        __syncthreads();
        sm[tid] += v;
        __syncthreads();
    }
    int run = bscan[blockIdx.x] + (sm[tid] - lsum);
#pragma unroll
    for (int j = 0; j < 4; j++) {
        int idx = g0 + j;
        if (idx < N) {
            row_ptr[idx] = run;
            inv_deg[idx] = d[j] > 0 ? 1.0f / (float)d[j] : 0.0f;
            run += d[j];
        }
    }
}

// ---------------- weight prep: f32 -> bf16, transposed ----------------
__global__ __launch_bounds__(256) void prep_w(const float* __restrict__ wl,
                                              const float* __restrict__ wr,
                                              const float* __restrict__ wres,
                                              const float* __restrict__ wfc,
                                              u16* __restrict__ WtL,
                                              u16* __restrict__ WresT,
                                              u16* __restrict__ WfcT) {
    int gid = blockIdx.x * 256 + threadIdx.x;
    int gstr = gridDim.x * 256;
    for (int idx = gid; idx < 3 * 64 * 128; idx += gstr) {
        int l = idx >> 13;
        int rem = idx & 8191;
        int n = rem >> 7;
        int k = rem & 127;
        float v = (k < 64) ? wl[l * 4096 + k * 64 + n] : wr[l * 4096 + (k - 64) * 64 + n];
        WtL[idx] = f2b(v);
    }
    for (int idx = gid; idx < 4096; idx += gstr) {
        int n = idx >> 6, k = idx & 63;
        WresT[idx] = f2b(wres[k * 64 + n]);
        WfcT[idx] = f2b(wfc[k * 64 + n]);
    }
}

// ---------------- f32 -> bf16 mirror ----------------
__global__ __launch_bounds__(256) void cvt_kernel(const float* __restrict__ xf,
                                                  u16* __restrict__ xb, int total4) {
    int i = blockIdx.x * 256 + threadIdx.x;
    int stride = gridDim.x * 256;
    for (; i < total4; i += stride) {
        float4 v = *(const float4*)(xf + i * 4);
        ushort4 o;
        o.x = f2b(v.x); o.y = f2b(v.y); o.z = f2b(v.z); o.w = f2b(v.w);
        *(ushort4*)(xb + i * 4) = o;
    }
}

// ---------------- mean aggregation (pull, CSR), 16 edges in flight ----------------
__global__ __launch_bounds__(256) void agg_kernel(const u16* __restrict__ xb,
                                                  const int* __restrict__ row_ptr,
                                                  const int* __restrict__ col,
                                                  const float* __restrict__ inv_deg,
                                                  u16* __restrict__ agg, int N) {
    int node = (blockIdx.x * 256 + threadIdx.x) >> 6;
    int lane = threadIdx.x & 63;
    if (node >= N) return;
    int beg = row_ptr[node], end = row_ptr[node + 1];
    int slot = lane >> 3;     // which of 8 concurrent edges
    int chunk = lane & 7;     // which 8-feature chunk of the row

    float a0 = 0, a1 = 0, a2 = 0, a3 = 0, a4 = 0, a5 = 0, a6 = 0, a7 = 0;
    int e = beg + slot;
    for (; e + 8 < end; e += 16) {          // 2 gathers in flight per lane
        int s0 = col[e], s1 = col[e + 8];
        uint4 v0 = *(const uint4*)(xb + s0 * D + chunk * 8);
        uint4 v1 = *(const uint4*)(xb + s1 * D + chunk * 8);
        a0 += u2f_lo(v0.x); a1 += u2f_hi(v0.x);
        a2 += u2f_lo(v0.y); a3 += u2f_hi(v0.y);
        a4 += u2f_lo(v0.z); a5 += u2f_hi(v0.z);
        a6 += u2f_lo(v0.w); a7 += u2f_hi(v0.w);
        a0 += u2f_lo(v1.x); a1 += u2f_hi(v1.x);
        a2 += u2f_lo(v1.y); a3 += u2f_hi(v1.y);
        a4 += u2f_lo(v1.z); a5 += u2f_hi(v1.z);
        a6 += u2f_lo(v1.w); a7 += u2f_hi(v1.w);
    }
    if (e < end) {
        int s0 = col[e];
        uint4 v0 = *(const uint4*)(xb + s0 * D + chunk * 8);
        a0 += u2f_lo(v0.x); a1 += u2f_hi(v0.x);
        a2 += u2f_lo(v0.y); a3 += u2f_hi(v0.y);
        a4 += u2f_lo(v0.z); a5 += u2f_hi(v0.z);
        a6 += u2f_lo(v0.w); a7 += u2f_hi(v0.w);
    }
#pragma unroll
    for (int off = 8; off < 64; off <<= 1) {
        a0 += __shfl_xor(a0, off, 64);
        a1 += __shfl_xor(a1, off, 64);
        a2 += __shfl_xor(a2, off, 64);
        a3 += __shfl_xor(a3, off, 64);
        a4 += __shfl_xor(a4, off, 64);
        a5 += __shfl_xor(a5, off, 64);
        a6 += __shfl_xor(a6, off, 64);
        a7 += __shfl_xor(a7, off, 64);
    }
    if (slot == 0) {
        float m = inv_deg[node];
        uint4 o;
        o.x = (unsigned)f2b(a0 * m) | ((unsigned)f2b(a1 * m) << 16);
        o.y = (unsigned)f2b(a2 * m) | ((unsigned)f2b(a3 * m) << 16);
        o.z = (unsigned)f2b(a4 * m) | ((unsigned)f2b(a5 * m) << 16);
        o.w = (unsigned)f2b(a6 * m) | ((unsigned)f2b(a7 * m) << 16);
        *(uint4*)(agg + node * D + chunk * 8) = o;
    }
}

// ---------------- fused SAGE layer ----------------
__global__ __launch_bounds__(256) void layer_kernel(const u16* __restrict__ agg,
                                                    const u16* __restrict__ xbin,
                                                    const float* __restrict__ xfin,
                                                    const u16* __restrict__ Wt,
                                                    const float* __restrict__ bl,
                                                    const float* __restrict__ gam,
                                                    const float* __restrict__ bet,
                                                    const u16* __restrict__ WresT,
                                                    const float* __restrict__ bres,
                                                    float* __restrict__ xfout,
                                                    u16* __restrict__ xbout,
                                                    int N, int layer0) {
    __shared__ __align__(16) u16 sA[64 * LPITCH];
    __shared__ __align__(16) u16 sB[64 * LPITCH];
    __shared__ __align__(16) u16 sR[64 * SPITCH];
    int tid = threadIdx.x;
    int base = blockIdx.x * 64;

#pragma unroll
    for (int i = 0; i < 4; i++) {
        int idx = i * 256 + tid;
        int r = idx >> 4, c = idx & 15;
        int node = base + r;
        uint4 v = make_uint4(0, 0, 0, 0);
        if (node < N) {
            const u16* s = (c < 8) ? (agg + node * D + c * 8) : (xbin + node * D + (c - 8) * 8);
            v = *(const uint4*)s;
        }
        *(uint4*)&sA[r * LPITCH + c * 8] = v;
    }
#pragma unroll
    for (int i = 0; i < 4; i++) {
        int idx = i * 256 + tid;
        int r = idx >> 4, c = idx & 15;
        *(uint4*)&sB[r * LPITCH + c * 8] = *(const uint4*)(Wt + idx * 8);
    }
    if (layer0) {
#pragma unroll
        for (int i = 0; i < 2; i++) {
            int idx = i * 256 + tid;
            int r = idx >> 3, c = idx & 7;
            *(uint4*)&sR[r * SPITCH + c * 8] = *(const uint4*)(WresT + idx * 8);
        }
    }
    __syncthreads();

    int lane = tid & 63;
    int w = tid >> 6;
    int q = lane >> 4;
    int ln = lane & 15;

    f32x4 acc[4] = {{0, 0, 0, 0}, {0, 0, 0, 0}, {0, 0, 0, 0}, {0, 0, 0, 0}};
    f32x4 accr[4] = {{0, 0, 0, 0}, {0, 0, 0, 0}, {0, 0, 0, 0}, {0, 0, 0, 0}};
    const u16* aRow = &sA[(w * 16 + ln) * LPITCH];

#pragma unroll
    for (int c = 0; c < 4; c++) {       // K = 128
        bf16x8 a = ld_frag(&aRow[c * 32 + q * 8]);
#pragma unroll
        for (int t = 0; t < 4; t++) {
            bf16x8 b = ld_frag(&sB[(t * 16 + ln) * LPITCH + c * 32 + q * 8]);
            acc[t] = __builtin_amdgcn_mfma_f32_16x16x32_bf16(a, b, acc[t], 0, 0, 0);
        }
    }
    if (layer0) {
#pragma unroll
        for (int c = 0; c < 2; c++) {
            bf16x8 a = ld_frag(&aRow[64 + c * 32 + q * 8]);
#pragma unroll
            for (int t = 0; t < 4; t++) {
                bf16x8 b = ld_frag(&sR[(t * 16 + ln) * SPITCH + c * 32 + q * 8]);
                accr[t] = __builtin_amdgcn_mfma_f32_16x16x32_bf16(a, b, accr[t], 0, 0, 0);
            }
        }
    }

    float bcol[4], gcol[4], btcol[4], brcol[4];
#pragma unroll
    for (int t = 0; t < 4; t++) {
        int colI = t * 16 + ln;
        bcol[t] = bl[colI];
        gcol[t] = gam[colI];
        btcol[t] = bet[colI];
        brcol[t] = layer0 ? bres[colI] : 0.f;
    }
#pragma unroll
    for (int t = 0; t < 4; t++)
#pragma unroll
        for (int r = 0; r < 4; r++) acc[t][r] += bcol[t];

    float ps[4], pq[4];
#pragma unroll
    for (int r = 0; r < 4; r++) {
        float s = 0, s2 = 0;
#pragma unroll
        for (int t = 0; t < 4; t++) { float h = acc[t][r]; s += h; s2 += h * h; }
        ps[r] = s; pq[r] = s2;
    }
    for (int off = 1; off < 16; off <<= 1) {
#pragma unroll
        for (int r = 0; r < 4; r++) {
            ps[r] += __shfl_xor(ps[r], off, 64);
            pq[r] += __shfl_xor(pq[r], off, 64);
        }
    }
#pragma unroll
    for (int r = 0; r < 4; r++) {
        int nb = w * 16 + q * 4 + r;
        int node = base + nb;
        if (node >= N) continue;
        float mu = ps[r] * (1.f / 64.f);
        float var = pq[r] * (1.f / 64.f) - mu * mu;
        var = var < 0.f ? 0.f : var;
        float rstd = rsqrtf(var + 1e-5f);
#pragma unroll
        for (int t = 0; t < 4; t++) {
            int colI = t * 16 + ln;
            float hn = (acc[t][r] - mu) * rstd * gcol[t] + btcol[t];
            hn = hn > 0.f ? hn : 0.f;
            float res = layer0 ? (accr[t][r] + brcol[t]) : xfin[node * D + colI];
            float v = hn + res;
            xfout[node * D + colI] = v;
            xbout[node * D + colI] = f2b(v);
        }
    }
}

// ---------------- final fc ----------------
__global__ __launch_bounds__(256) void fc_kernel(const u16* __restrict__ xbin,
                                                 const u16* __restrict__ WfcT,
                                                 const float* __restrict__ bfc,
                                                 float* __restrict__ out, int N) {
    __shared__ __align__(16) u16 sA[64 * SPITCH];
    __shared__ __align__(16) u16 sB[64 * SPITCH];
    int tid = threadIdx.x;
    int base = blockIdx.x * 64;
#pragma unroll
    for (int i = 0; i < 2; i++) {
        int idx = i * 256 + tid;
        int r = idx >> 3, c = idx & 7;
        int node = base + r;
        uint4 v = make_uint4(0, 0, 0, 0);
        if (node < N) v = *(const uint4*)(xbin + node * D + c * 8);
        *(uint4*)&sA[r * SPITCH + c * 8] = v;
        *(uint4*)&sB[r * SPITCH + c * 8] = *(const uint4*)(WfcT + idx * 8);
    }
    __syncthreads();
    int lane = tid & 63;
    int w = tid >> 6, q = lane >> 4, ln = lane & 15;
    f32x4 acc[4] = {{0, 0, 0, 0}, {0, 0, 0, 0}, {0, 0, 0, 0}, {0, 0, 0, 0}};
#pragma unroll
    for (int c = 0; c < 2; c++) {
        bf16x8 a = ld_frag(&sA[(w * 16 + ln) * SPITCH + c * 32 + q * 8]);
#pragma unroll
        for (int t = 0; t < 4; t++) {
            bf16x8 b = ld_frag(&sB[(t * 16 + ln) * SPITCH + c * 32 + q * 8]);
            acc[t] = __builtin_amdgcn_mfma_f32_16x16x32_bf16(a, b, acc[t], 0, 0, 0);
        }
    }
#pragma unroll
    for (int r = 0; r < 4; r++) {
        int node = base + w * 16 + q * 4 + r;
        if (node >= N) continue;
#pragma unroll
        for (int t = 0; t < 4; t++) {
            int colI = t * 16 + ln;
            out[node * D + colI] = acc[t][r] + bfc[colI];
        }
    }
}

extern "C" void kernel_launch(void* const* d_in, const int* in_sizes, int n_in,
                              void* d_out, int out_size, void* d_ws, size_t ws_size,
                              hipStream_t stream) {
    const float* x_in = (const float*)d_in[0];
    const int* e_src = (const int*)d_in[1];
    const int* e_dst = (const int*)d_in[2];
    const float* w_l = (const float*)d_in[3];
    const float* b_l = (const float*)d_in[4];
    const float* w_r = (const float*)d_in[5];
    const float* gam = (const float*)d_in[6];
    const float* bet = (const float*)d_in[7];
    const float* w_res = (const float*)d_in[8];
    const float* b_res = (const float*)d_in[9];
    const float* w_fc = (const float*)d_in[10];
    const float* b_fc = (const float*)d_in[11];
    float* out = (float*)d_out;

    const int N = in_sizes[0] / D;
    const int E = in_sizes[1];
    const int NB = (N + 1023) / 1024;

    // bucket shift: nbuck <= 256 and bucket node-range <= 1024 (LDS in binC)
    int shift = 9;
    while ((((N - 1) >> shift) + 1) > 256 && shift < 10) shift++;
    const int nbuck = ((N - 1) >> shift) + 1;
    const int eper = (E + CHUNKS - 1) / CHUNKS;

    size_t o = 0;
    auto carve = [&](size_t bytes) {
        size_t cur = o;
        o += (bytes + 255) & ~(size_t)255;
        return (char*)d_ws + cur;
    };
    int* deg = (int*)carve((size_t)N * 4);
    int* row_ptr = (int*)carve((size_t)(N + 1) * 4);
    int* bsum = (int*)carve((size_t)NB * 4);
    int* bscan = (int*)carve((size_t)NB * 4);
    float* inv_deg = (float*)carve((size_t)N * 4);
    int* colA = (int*)carve((size_t)E * 4);
    int* staging = (int*)carve((size_t)E * 4);
    int* Hh = (int*)carve((size_t)CHUNKS * nbuck * 4);
    int* Oo = (int*)carve((size_t)CHUNKS * nbuck * 4);
    u16* WtL = (u16*)carve(3 * 64 * 128 * 2);
    u16* WresT = (u16*)carve(64 * 64 * 2);
    u16* WfcT = (u16*)carve(64 * 64 * 2);
    u16* xbA = (u16*)carve((size_t)N * D * 2);
    u16* xbB = (u16*)carve((size_t)N * D * 2);
    u16* aggB = (u16*)carve((size_t)N * D * 2);
    float* xf1 = (float*)carve((size_t)N * D * 4);
    float* xf2 = out;

    hipMemsetAsync(deg, 0, (size_t)N * 4, stream);

    // CSR build (binned)
    binA_kernel<<<CHUNKS, 256, 0, stream>>>(e_dst, E, deg, Hh, shift, nbuck, eper);
    bsum_kernel<<<NB, 256, 0, stream>>>(deg, N, bsum);
    bscan_kernel<<<1, 256, 0, stream>>>(bsum, NB, bscan, row_ptr, N);
    scan_kernel<<<NB, 256, 0, stream>>>(deg, bscan, N, row_ptr, inv_deg);
    binS2_kernel<<<nbuck, 256, 0, stream>>>(Hh, row_ptr, Oo, shift, nbuck, N);
    binB_kernel<<<CHUNKS, 256, 0, stream>>>(e_src, e_dst, E, Oo, staging, shift, nbuck, eper);
    binC_kernel<<<nbuck, 256, 0, stream>>>(staging, row_ptr, deg, colA, shift, N);

    prep_w<<<32, 256, 0, stream>>>(w_l, w_r, w_res, w_fc, WtL, WresT, WfcT);
    cvt_kernel<<<1024, 256, 0, stream>>>(x_in, xbA, N * D / 4);

    int gridN = (N + 3) / 4;
    int gridT = (N + 63) / 64;

    // layer 0: (x_in, xbA) -> (xf1, xbB)
    agg_kernel<<<gridN, 256, 0, stream>>>(xbA, row_ptr, colA, inv_deg, aggB, N);
    layer_kernel<<<gridT, 256, 0, stream>>>(aggB, xbA, x_in, WtL, b_l, gam, bet,
                                            WresT, b_res, xf1, xbB, N, 1);
    // layer 1: (xf1, xbB) -> (xf2=d_out, xbA)
    agg_kernel<<<gridN, 256, 0, stream>>>(xbB, row_ptr, colA, inv_deg, aggB, N);
    layer_kernel<<<gridT, 256, 0, stream>>>(aggB, xbB, xf1, WtL + 8192, b_l + 64,
                                            gam + 64, bet + 64, WresT, b_res,
                                            xf2, xbA, N, 0);
    // layer 2: (xf2, xbA) -> (xf1 [discarded], xbB)
    agg_kernel<<<gridN, 256, 0, stream>>>(xbA, row_ptr, colA, inv_deg, aggB, N);
    layer_kernel<<<gridT, 256, 0, stream>>>(aggB, xbA, xf2, WtL + 16384, b_l + 128,
                                            gam + 128, bet + 128, WresT, b_res,
                                            xf1, xbB, N, 0);
    // final fc: xbB -> out
    fc_kernel<<<gridT, 256, 0, stream>>>(xbB, WfcT, b_fc, out, N);
}

// Round 5
// 352.717 us; speedup vs baseline: 1.8047x; 1.1852x over previous
//
#include <hip/hip_runtime.h>

typedef unsigned short u16;
typedef __bf16 bf16x8 __attribute__((ext_vector_type(8)));
typedef float f32x4 __attribute__((ext_vector_type(4)));

#define D 64
#define LPITCH 136   // 128 + 8 bf16 pad
#define SPITCH 72    // 64 + 8 bf16 pad
#define CHUNKS 512   // edge-array partitions for binning
#define BSHIFT 9     // 512 nodes per bucket (nbuck <= 256 for N <= 131072)

__device__ __forceinline__ float b2f(u16 u) {
    unsigned v = ((unsigned)u) << 16;
    float f;
    __builtin_memcpy(&f, &v, 4);
    return f;
}
__device__ __forceinline__ float u2f_lo(unsigned u) {
    unsigned v = u << 16;
    float f;
    __builtin_memcpy(&f, &v, 4);
    return f;
}
__device__ __forceinline__ float u2f_hi(unsigned u) {
    unsigned v = u & 0xFFFF0000u;
    float f;
    __builtin_memcpy(&f, &v, 4);
    return f;
}
__device__ __forceinline__ u16 f2b(float f) {
    unsigned u;
    __builtin_memcpy(&u, &f, 4);
    u = u + 0x7FFFu + ((u >> 16) & 1u);   // RNE
    return (u16)(u >> 16);
}
__device__ __forceinline__ bf16x8 ld_frag(const u16* p) {
    union { uint4 u; bf16x8 b; } cv;
    cv.u = *(const uint4*)p;
    return cv.b;
}

// ---------------- binned CSR build (no global atomics anywhere) ----------------
// binA: per-chunk bucket histogram in LDS only
__global__ __launch_bounds__(256) void binA_kernel(const int* __restrict__ dst, int E,
                                                   int* __restrict__ H,   // [CHUNKS][nbuck]
                                                   int nbuck, int eper) {
    __shared__ int hist[256];
    int t = threadIdx.x;
    int c = blockIdx.x;
    hist[t] = 0;
    __syncthreads();
    int beg = c * eper;
    int end = min(beg + eper, E);
    for (int i = beg + t; i < end; i += 256) {
        atomicAdd(&hist[dst[i] >> BSHIFT], 1);
    }
    __syncthreads();
    if (t < nbuck) H[c * nbuck + t] = hist[t];
}

// binS2: per-bucket scan of chunk counts -> RELATIVE staging offsets + bucket total T[b]
__global__ __launch_bounds__(256) void binS2_kernel(const int* __restrict__ H,
                                                    int* __restrict__ Orel,
                                                    int* __restrict__ T,
                                                    int nbuck) {
    __shared__ int ss[256];
    int b = blockIdx.x;
    int t = threadIdx.x;
    int h0 = H[(2 * t) * nbuck + b];
    int h1 = H[(2 * t + 1) * nbuck + b];
    ss[t] = h0 + h1;
    __syncthreads();
    for (int off = 1; off < 256; off <<= 1) {   // Hillis-Steele inclusive
        int v = (t >= off) ? ss[t - off] : 0;
        __syncthreads();
        ss[t] += v;
        __syncthreads();
    }
    int excl = ss[t] - h0 - h1;
    Orel[(2 * t) * nbuck + b] = excl;
    Orel[(2 * t + 1) * nbuck + b] = excl + h0;
    if (t == 255) T[b] = ss[255];
}

// binT: exclusive scan of bucket totals -> base[b]; base[nbuck] = row_ptr[N] = E
__global__ __launch_bounds__(256) void binT_kernel(const int* __restrict__ T, int nbuck,
                                                   int* __restrict__ base,
                                                   int* __restrict__ row_ptr, int N) {
    __shared__ int sm[256];
    int t = threadIdx.x;
    int v = (t < nbuck) ? T[t] : 0;
    sm[t] = v;
    __syncthreads();
    for (int off = 1; off < 256; off <<= 1) {
        int u = (t >= off) ? sm[t - off] : 0;
        __syncthreads();
        sm[t] += u;
        __syncthreads();
    }
    if (t < nbuck) base[t] = sm[t] - v;     // exclusive
    if (t == 255) {
        base[nbuck] = sm[255];
        row_ptr[N] = sm[255];
    }
}

// binB: scatter packed (src | local_dst<<17) into bucket-grouped staging
__global__ __launch_bounds__(256) void binB_kernel(const int* __restrict__ src,
                                                   const int* __restrict__ dst, int E,
                                                   const int* __restrict__ base,
                                                   const int* __restrict__ Orel,
                                                   int* __restrict__ staging,
                                                   int nbuck, int eper) {
    __shared__ int pos[256];
    int t = threadIdx.x;
    int c = blockIdx.x;
    if (t < nbuck) pos[t] = base[t] + Orel[c * nbuck + t];
    __syncthreads();
    int beg = c * eper;
    int end = min(beg + eper, E);
    const int mask = (1 << BSHIFT) - 1;
    for (int i = beg + t; i < end; i += 256) {
        int d = dst[i];
        int b = d >> BSHIFT;
        int p = atomicAdd(&pos[b], 1);
        staging[p] = src[i] | ((d & mask) << 17);
    }
}

// binC: block per bucket; degree hist + local scan + col scatter, all in LDS
__global__ __launch_bounds__(256) void binC_kernel(const int* __restrict__ staging,
                                                   const int* __restrict__ base,
                                                   int* __restrict__ row_ptr,
                                                   float* __restrict__ inv_deg,
                                                   int* __restrict__ col, int N) {
    __shared__ int cnt[512];
    __shared__ int lrp[512];
    __shared__ int sm[256];
    int b = blockIdx.x;
    int t = threadIdx.x;
    int node0 = b << BSHIFT;
    int nn = min(1 << BSHIFT, N - node0);
    cnt[t] = 0;
    cnt[t + 256] = 0;
    __syncthreads();
    int sbeg = base[b], send = base[b + 1];
    // pass 1: degree histogram
    for (int i = sbeg + t; i < send; i += 256) {
        atomicAdd(&cnt[staging[i] >> 17], 1);
    }
    __syncthreads();
    // exclusive scan over 512 entries (2 per thread)
    int c0 = cnt[2 * t], c1 = cnt[2 * t + 1];
    sm[t] = c0 + c1;
    __syncthreads();
    for (int off = 1; off < 256; off <<= 1) {
        int v = (t >= off) ? sm[t - off] : 0;
        __syncthreads();
        sm[t] += v;
        __syncthreads();
    }
    int excl = sm[t] - c0 - c1;
    lrp[2 * t] = excl;
    lrp[2 * t + 1] = excl + c0;
    __syncthreads();
    // write row_ptr + inv_deg
    for (int i = t; i < nn; i += 256) {
        row_ptr[node0 + i] = sbeg + lrp[i];
        int dd = cnt[i];
        inv_deg[node0 + i] = dd > 0 ? 1.0f / (float)dd : 0.0f;
    }
    __syncthreads();
    // pass 2: scatter col via LDS countdown (staging slice is L2-hot from pass 1)
    for (int i = sbeg + t; i < send; i += 256) {
        int word = staging[i];
        int ld = word >> 17;
        int k = atomicSub(&cnt[ld], 1) - 1;
        col[sbeg + lrp[ld] + k] = word & 0x1FFFF;
    }
}

// ---------------- weight prep: f32 -> bf16, transposed ----------------
__global__ __launch_bounds__(256) void prep_w(const float* __restrict__ wl,
                                              const float* __restrict__ wr,
                                              const float* __restrict__ wres,
                                              const float* __restrict__ wfc,
                                              u16* __restrict__ WtL,
                                              u16* __restrict__ WresT,
                                              u16* __restrict__ WfcT) {
    int gid = blockIdx.x * 256 + threadIdx.x;
    int gstr = gridDim.x * 256;
    for (int idx = gid; idx < 3 * 64 * 128; idx += gstr) {
        int l = idx >> 13;
        int rem = idx & 8191;
        int n = rem >> 7;
        int k = rem & 127;
        float v = (k < 64) ? wl[l * 4096 + k * 64 + n] : wr[l * 4096 + (k - 64) * 64 + n];
        WtL[idx] = f2b(v);
    }
    for (int idx = gid; idx < 4096; idx += gstr) {
        int n = idx >> 6, k = idx & 63;
        WresT[idx] = f2b(wres[k * 64 + n]);
        WfcT[idx] = f2b(wfc[k * 64 + n]);
    }
}

// ---------------- f32 -> bf16 mirror ----------------
__global__ __launch_bounds__(256) void cvt_kernel(const float* __restrict__ xf,
                                                  u16* __restrict__ xb, int total4) {
    int i = blockIdx.x * 256 + threadIdx.x;
    int stride = gridDim.x * 256;
    for (; i < total4; i += stride) {
        float4 v = *(const float4*)(xf + i * 4);
        ushort4 o;
        o.x = f2b(v.x); o.y = f2b(v.y); o.z = f2b(v.z); o.w = f2b(v.w);
        *(ushort4*)(xb + i * 4) = o;
    }
}

// ---------------- mean aggregation (pull, CSR), up to 32 edges in flight ----------------
__global__ __launch_bounds__(256) void agg_kernel(const u16* __restrict__ xb,
                                                  const int* __restrict__ row_ptr,
                                                  const int* __restrict__ col,
                                                  const float* __restrict__ inv_deg,
                                                  u16* __restrict__ agg, int N) {
    int node = (blockIdx.x * 256 + threadIdx.x) >> 6;
    int lane = threadIdx.x & 63;
    if (node >= N) return;
    int beg = row_ptr[node], end = row_ptr[node + 1];
    int slot = lane >> 3;     // which of 8 concurrent edges
    int chunk = lane & 7;     // which 8-feature chunk of the row

    float a0 = 0, a1 = 0, a2 = 0, a3 = 0, a4 = 0, a5 = 0, a6 = 0, a7 = 0;
    int e = beg + slot;
#define ACC(v)                                          \
    a0 += u2f_lo(v.x); a1 += u2f_hi(v.x);               \
    a2 += u2f_lo(v.y); a3 += u2f_hi(v.y);               \
    a4 += u2f_lo(v.z); a5 += u2f_hi(v.z);               \
    a6 += u2f_lo(v.w); a7 += u2f_hi(v.w);
    for (; e + 24 < end; e += 32) {         // 4 gathers in flight
        int s0 = col[e], s1 = col[e + 8], s2 = col[e + 16], s3 = col[e + 24];
        uint4 v0 = *(const uint4*)(xb + s0 * D + chunk * 8);
        uint4 v1 = *(const uint4*)(xb + s1 * D + chunk * 8);
        uint4 v2 = *(const uint4*)(xb + s2 * D + chunk * 8);
        uint4 v3 = *(const uint4*)(xb + s3 * D + chunk * 8);
        ACC(v0) ACC(v1) ACC(v2) ACC(v3)
    }
    for (; e + 8 < end; e += 16) {          // 2 gathers in flight
        int s0 = col[e], s1 = col[e + 8];
        uint4 v0 = *(const uint4*)(xb + s0 * D + chunk * 8);
        uint4 v1 = *(const uint4*)(xb + s1 * D + chunk * 8);
        ACC(v0) ACC(v1)
    }
    if (e < end) {
        int s0 = col[e];
        uint4 v0 = *(const uint4*)(xb + s0 * D + chunk * 8);
        ACC(v0)
    }
#undef ACC
#pragma unroll
    for (int off = 8; off < 64; off <<= 1) {
        a0 += __shfl_xor(a0, off, 64);
        a1 += __shfl_xor(a1, off, 64);
        a2 += __shfl_xor(a2, off, 64);
        a3 += __shfl_xor(a3, off, 64);
        a4 += __shfl_xor(a4, off, 64);
        a5 += __shfl_xor(a5, off, 64);
        a6 += __shfl_xor(a6, off, 64);
        a7 += __shfl_xor(a7, off, 64);
    }
    if (slot == 0) {
        float m = inv_deg[node];
        uint4 o;
        o.x = (unsigned)f2b(a0 * m) | ((unsigned)f2b(a1 * m) << 16);
        o.y = (unsigned)f2b(a2 * m) | ((unsigned)f2b(a3 * m) << 16);
        o.z = (unsigned)f2b(a4 * m) | ((unsigned)f2b(a5 * m) << 16);
        o.w = (unsigned)f2b(a6 * m) | ((unsigned)f2b(a7 * m) << 16);
        *(uint4*)(agg + node * D + chunk * 8) = o;
    }
}

// ---------------- fused SAGE layer ----------------
__global__ __launch_bounds__(256) void layer_kernel(const u16* __restrict__ agg,
                                                    const u16* __restrict__ xbin,
                                                    const float* __restrict__ xfin,
                                                    const u16* __restrict__ Wt,
                                                    const float* __restrict__ bl,
                                                    const float* __restrict__ gam,
                                                    const float* __restrict__ bet,
                                                    const u16* __restrict__ WresT,
                                                    const float* __restrict__ bres,
                                                    float* __restrict__ xfout,
                                                    u16* __restrict__ xbout,
                                                    int N, int layer0) {
    __shared__ __align__(16) u16 sA[64 * LPITCH];
    __shared__ __align__(16) u16 sB[64 * LPITCH];
    __shared__ __align__(16) u16 sR[64 * SPITCH];
    int tid = threadIdx.x;
    int base = blockIdx.x * 64;

#pragma unroll
    for (int i = 0; i < 4; i++) {
        int idx = i * 256 + tid;
        int r = idx >> 4, c = idx & 15;
        int node = base + r;
        uint4 v = make_uint4(0, 0, 0, 0);
        if (node < N) {
            const u16* s = (c < 8) ? (agg + node * D + c * 8) : (xbin + node * D + (c - 8) * 8);
            v = *(const uint4*)s;
        }
        *(uint4*)&sA[r * LPITCH + c * 8] = v;
    }
#pragma unroll
    for (int i = 0; i < 4; i++) {
        int idx = i * 256 + tid;
        int r = idx >> 4, c = idx & 15;
        *(uint4*)&sB[r * LPITCH + c * 8] = *(const uint4*)(Wt + idx * 8);
    }
    if (layer0) {
#pragma unroll
        for (int i = 0; i < 2; i++) {
            int idx = i * 256 + tid;
            int r = idx >> 3, c = idx & 7;
            *(uint4*)&sR[r * SPITCH + c * 8] = *(const uint4*)(WresT + idx * 8);
        }
    }
    __syncthreads();

    int lane = tid & 63;
    int w = tid >> 6;
    int q = lane >> 4;
    int ln = lane & 15;

    f32x4 acc[4] = {{0, 0, 0, 0}, {0, 0, 0, 0}, {0, 0, 0, 0}, {0, 0, 0, 0}};
    f32x4 accr[4] = {{0, 0, 0, 0}, {0, 0, 0, 0}, {0, 0, 0, 0}, {0, 0, 0, 0}};
    const u16* aRow = &sA[(w * 16 + ln) * LPITCH];

#pragma unroll
    for (int c = 0; c < 4; c++) {       // K = 128
        bf16x8 a = ld_frag(&aRow[c * 32 + q * 8]);
#pragma unroll
        for (int t = 0; t < 4; t++) {
            bf16x8 b = ld_frag(&sB[(t * 16 + ln) * LPITCH + c * 32 + q * 8]);
            acc[t] = __builtin_amdgcn_mfma_f32_16x16x32_bf16(a, b, acc[t], 0, 0, 0);
        }
    }
    if (layer0) {
#pragma unroll
        for (int c = 0; c < 2; c++) {
            bf16x8 a = ld_frag(&aRow[64 + c * 32 + q * 8]);
#pragma unroll
            for (int t = 0; t < 4; t++) {
                bf16x8 b = ld_frag(&sR[(t * 16 + ln) * SPITCH + c * 32 + q * 8]);
                accr[t] = __builtin_amdgcn_mfma_f32_16x16x32_bf16(a, b, accr[t], 0, 0, 0);
            }
        }
    }

    float bcol[4], gcol[4], btcol[4], brcol[4];
#pragma unroll
    for (int t = 0; t < 4; t++) {
        int colI = t * 16 + ln;
        bcol[t] = bl[colI];
        gcol[t] = gam[colI];
        btcol[t] = bet[colI];
        brcol[t] = layer0 ? bres[colI] : 0.f;
    }
#pragma unroll
    for (int t = 0; t < 4; t++)
#pragma unroll
        for (int r = 0; r < 4; r++) acc[t][r] += bcol[t];

    float ps[4], pq[4];
#pragma unroll
    for (int r = 0; r < 4; r++) {
        float s = 0, s2 = 0;
#pragma unroll
        for (int t = 0; t < 4; t++) { float h = acc[t][r]; s += h; s2 += h * h; }
        ps[r] = s; pq[r] = s2;
    }
    for (int off = 1; off < 16; off <<= 1) {
#pragma unroll
        for (int r = 0; r < 4; r++) {
            ps[r] += __shfl_xor(ps[r], off, 64);
            pq[r] += __shfl_xor(pq[r], off, 64);
        }
    }
#pragma unroll
    for (int r = 0; r < 4; r++) {
        int nb = w * 16 + q * 4 + r;
        int node = base + nb;
        if (node >= N) continue;
        float mu = ps[r] * (1.f / 64.f);
        float var = pq[r] * (1.f / 64.f) - mu * mu;
        var = var < 0.f ? 0.f : var;
        float rstd = rsqrtf(var + 1e-5f);
#pragma unroll
        for (int t = 0; t < 4; t++) {
            int colI = t * 16 + ln;
            float hn = (acc[t][r] - mu) * rstd * gcol[t] + btcol[t];
            hn = hn > 0.f ? hn : 0.f;
            float res = layer0 ? (accr[t][r] + brcol[t]) : xfin[node * D + colI];
            float v = hn + res;
            xfout[node * D + colI] = v;
            xbout[node * D + colI] = f2b(v);
        }
    }
}

// ---------------- final fc ----------------
__global__ __launch_bounds__(256) void fc_kernel(const u16* __restrict__ xbin,
                                                 const u16* __restrict__ WfcT,
                                                 const float* __restrict__ bfc,
                                                 float* __restrict__ out, int N) {
    __shared__ __align__(16) u16 sA[64 * SPITCH];
    __shared__ __align__(16) u16 sB[64 * SPITCH];
    int tid = threadIdx.x;
    int base = blockIdx.x * 64;
#pragma unroll
    for (int i = 0; i < 2; i++) {
        int idx = i * 256 + tid;
        int r = idx >> 3, c = idx & 7;
        int node = base + r;
        uint4 v = make_uint4(0, 0, 0, 0);
        if (node < N) v = *(const uint4*)(xbin + node * D + c * 8);
        *(uint4*)&sA[r * SPITCH + c * 8] = v;
        *(uint4*)&sB[r * SPITCH + c * 8] = *(const uint4*)(WfcT + idx * 8);
    }
    __syncthreads();
    int lane = tid & 63;
    int w = tid >> 6, q = lane >> 4, ln = lane & 15;
    f32x4 acc[4] = {{0, 0, 0, 0}, {0, 0, 0, 0}, {0, 0, 0, 0}, {0, 0, 0, 0}};
#pragma unroll
    for (int c = 0; c < 2; c++) {
        bf16x8 a = ld_frag(&sA[(w * 16 + ln) * SPITCH + c * 32 + q * 8]);
#pragma unroll
        for (int t = 0; t < 4; t++) {
            bf16x8 b = ld_frag(&sB[(t * 16 + ln) * SPITCH + c * 32 + q * 8]);
            acc[t] = __builtin_amdgcn_mfma_f32_16x16x32_bf16(a, b, acc[t], 0, 0, 0);
        }
    }
#pragma unroll
    for (int r = 0; r < 4; r++) {
        int node = base + w * 16 + q * 4 + r;
        if (node >= N) continue;
#pragma unroll
        for (int t = 0; t < 4; t++) {
            int colI = t * 16 + ln;
            out[node * D + colI] = acc[t][r] + bfc[colI];
        }
    }
}

extern "C" void kernel_launch(void* const* d_in, const int* in_sizes, int n_in,
                              void* d_out, int out_size, void* d_ws, size_t ws_size,
                              hipStream_t stream) {
    const float* x_in = (const float*)d_in[0];
    const int* e_src = (const int*)d_in[1];
    const int* e_dst = (const int*)d_in[2];
    const float* w_l = (const float*)d_in[3];
    const float* b_l = (const float*)d_in[4];
    const float* w_r = (const float*)d_in[5];
    const float* gam = (const float*)d_in[6];
    const float* bet = (const float*)d_in[7];
    const float* w_res = (const float*)d_in[8];
    const float* b_res = (const float*)d_in[9];
    const float* w_fc = (const float*)d_in[10];
    const float* b_fc = (const float*)d_in[11];
    float* out = (float*)d_out;

    const int N = in_sizes[0] / D;
    const int E = in_sizes[1];
    const int nbuck = ((N - 1) >> BSHIFT) + 1;   // <= 256 for N <= 131072
    const int eper = (E + CHUNKS - 1) / CHUNKS;

    size_t o = 0;
    auto carve = [&](size_t bytes) {
        size_t cur = o;
        o += (bytes + 255) & ~(size_t)255;
        return (char*)d_ws + cur;
    };
    int* row_ptr = (int*)carve((size_t)(N + 1) * 4);
    float* inv_deg = (float*)carve((size_t)N * 4);
    int* colA = (int*)carve((size_t)E * 4);
    int* staging = (int*)carve((size_t)E * 4);
    int* Hh = (int*)carve((size_t)CHUNKS * nbuck * 4);
    int* Orel = (int*)carve((size_t)CHUNKS * nbuck * 4);
    int* Tb = (int*)carve((size_t)nbuck * 4);
    int* baseB = (int*)carve((size_t)(nbuck + 1) * 4);
    u16* WtL = (u16*)carve(3 * 64 * 128 * 2);
    u16* WresT = (u16*)carve(64 * 64 * 2);
    u16* WfcT = (u16*)carve(64 * 64 * 2);
    u16* xbA = (u16*)carve((size_t)N * D * 2);
    u16* xbB = (u16*)carve((size_t)N * D * 2);
    u16* aggB = (u16*)carve((size_t)N * D * 2);
    float* xf1 = (float*)carve((size_t)N * D * 4);
    float* xf2 = out;

    // CSR build (binned, LDS-atomics only)
    binA_kernel<<<CHUNKS, 256, 0, stream>>>(e_dst, E, Hh, nbuck, eper);
    binS2_kernel<<<nbuck, 256, 0, stream>>>(Hh, Orel, Tb, nbuck);
    binT_kernel<<<1, 256, 0, stream>>>(Tb, nbuck, baseB, row_ptr, N);
    binB_kernel<<<CHUNKS, 256, 0, stream>>>(e_src, e_dst, E, baseB, Orel, staging, nbuck, eper);
    binC_kernel<<<nbuck, 256, 0, stream>>>(staging, baseB, row_ptr, inv_deg, colA, N);

    prep_w<<<32, 256, 0, stream>>>(w_l, w_r, w_res, w_fc, WtL, WresT, WfcT);
    cvt_kernel<<<1024, 256, 0, stream>>>(x_in, xbA, N * D / 4);

    int gridN = (N + 3) / 4;
    int gridT = (N + 63) / 64;

    // layer 0: (x_in, xbA) -> (xf1, xbB)
    agg_kernel<<<gridN, 256, 0, stream>>>(xbA, row_ptr, colA, inv_deg, aggB, N);
    layer_kernel<<<gridT, 256, 0, stream>>>(aggB, xbA, x_in, WtL, b_l, gam, bet,
                                            WresT, b_res, xf1, xbB, N, 1);
    // layer 1: (xf1, xbB) -> (xf2=d_out, xbA)
    agg_kernel<<<gridN, 256, 0, stream>>>(xbB, row_ptr, colA, inv_deg, aggB, N);
    layer_kernel<<<gridT, 256, 0, stream>>>(aggB, xbB, xf1, WtL + 8192, b_l + 64,
                                            gam + 64, bet + 64, WresT, b_res,
                                            xf2, xbA, N, 0);
    // layer 2: (xf2, xbA) -> (xf1 [discarded], xbB)
    agg_kernel<<<gridN, 256, 0, stream>>>(xbA, row_ptr, colA, inv_deg, aggB, N);
    layer_kernel<<<gridT, 256, 0, stream>>>(aggB, xbA, xf2, WtL + 16384, b_l + 128,
                                            gam + 128, bet + 128, WresT, b_res,
                                            xf1, xbB, N, 0);
    // final fc: xbB -> out
    fc_kernel<<<gridT, 256, 0, stream>>>(xbB, WfcT, b_fc, out, N);
}

// Round 6
// 289.888 us; speedup vs baseline: 2.1959x; 1.2167x over previous
//
#include <hip/hip_runtime.h>

typedef unsigned short u16;
typedef __bf16 bf16x8 __attribute__((ext_vector_type(8)));
typedef float f32x4 __attribute__((ext_vector_type(4)));

#define D 64
#define LPITCH 136   // 128 + 8 bf16 pad
#define SPITCH 72    // 64 + 8 bf16 pad
#define CHUNKS 512   // edge-array partitions for binning
#define BSHIFT 9     // 512 nodes per bucket (nbuck <= 256 for N <= 131072)

__device__ __forceinline__ float b2f(u16 u) {
    unsigned v = ((unsigned)u) << 16;
    float f;
    __builtin_memcpy(&f, &v, 4);
    return f;
}
__device__ __forceinline__ float u2f_lo(unsigned u) {
    unsigned v = u << 16;
    float f;
    __builtin_memcpy(&f, &v, 4);
    return f;
}
__device__ __forceinline__ float u2f_hi(unsigned u) {
    unsigned v = u & 0xFFFF0000u;
    float f;
    __builtin_memcpy(&f, &v, 4);
    return f;
}
__device__ __forceinline__ u16 f2b(float f) {
    unsigned u;
    __builtin_memcpy(&u, &f, 4);
    u = u + 0x7FFFu + ((u >> 16) & 1u);   // RNE
    return (u16)(u >> 16);
}
__device__ __forceinline__ bf16x8 ld_frag(const u16* p) {
    union { uint4 u; bf16x8 b; } cv;
    cv.u = *(const uint4*)p;
    return cv.b;
}

// ---------------- binned CSR build (no global atomics anywhere) ----------------
__global__ __launch_bounds__(256) void binA_kernel(const int* __restrict__ dst, int E,
                                                   int* __restrict__ H,   // [CHUNKS][nbuck]
                                                   int nbuck, int eper) {
    __shared__ int hist[256];
    int t = threadIdx.x;
    int c = blockIdx.x;
    hist[t] = 0;
    __syncthreads();
    int beg = c * eper;
    int end = min(beg + eper, E);
    for (int i = beg + t; i < end; i += 256) {
        atomicAdd(&hist[dst[i] >> BSHIFT], 1);
    }
    __syncthreads();
    if (t < nbuck) H[c * nbuck + t] = hist[t];
}

__global__ __launch_bounds__(256) void binS2_kernel(const int* __restrict__ H,
                                                    int* __restrict__ Orel,
                                                    int* __restrict__ T,
                                                    int nbuck) {
    __shared__ int ss[256];
    int b = blockIdx.x;
    int t = threadIdx.x;
    int h0 = H[(2 * t) * nbuck + b];
    int h1 = H[(2 * t + 1) * nbuck + b];
    ss[t] = h0 + h1;
    __syncthreads();
    for (int off = 1; off < 256; off <<= 1) {
        int v = (t >= off) ? ss[t - off] : 0;
        __syncthreads();
        ss[t] += v;
        __syncthreads();
    }
    int excl = ss[t] - h0 - h1;
    Orel[(2 * t) * nbuck + b] = excl;
    Orel[(2 * t + 1) * nbuck + b] = excl + h0;
    if (t == 255) T[b] = ss[255];
}

__global__ __launch_bounds__(256) void binT_kernel(const int* __restrict__ T, int nbuck,
                                                   int* __restrict__ base,
                                                   int* __restrict__ row_ptr, int N) {
    __shared__ int sm[256];
    int t = threadIdx.x;
    int v = (t < nbuck) ? T[t] : 0;
    sm[t] = v;
    __syncthreads();
    for (int off = 1; off < 256; off <<= 1) {
        int u = (t >= off) ? sm[t - off] : 0;
        __syncthreads();
        sm[t] += u;
        __syncthreads();
    }
    if (t < nbuck) base[t] = sm[t] - v;
    if (t == 255) {
        base[nbuck] = sm[255];
        row_ptr[N] = sm[255];
    }
}

__global__ __launch_bounds__(256) void binB_kernel(const int* __restrict__ src,
                                                   const int* __restrict__ dst, int E,
                                                   const int* __restrict__ base,
                                                   const int* __restrict__ Orel,
                                                   int* __restrict__ staging,
                                                   int nbuck, int eper) {
    __shared__ int pos[256];
    int t = threadIdx.x;
    int c = blockIdx.x;
    if (t < nbuck) pos[t] = base[t] + Orel[c * nbuck + t];
    __syncthreads();
    int beg = c * eper;
    int end = min(beg + eper, E);
    const int mask = (1 << BSHIFT) - 1;
    for (int i = beg + t; i < end; i += 256) {
        int d = dst[i];
        int b = d >> BSHIFT;
        int p = atomicAdd(&pos[b], 1);
        staging[p] = src[i] | ((d & mask) << 17);
    }
}

__global__ __launch_bounds__(256) void binC_kernel(const int* __restrict__ staging,
                                                   const int* __restrict__ base,
                                                   int* __restrict__ row_ptr,
                                                   float* __restrict__ inv_deg,
                                                   int* __restrict__ col, int N) {
    __shared__ int cnt[512];
    __shared__ int lrp[512];
    __shared__ int sm[256];
    int b = blockIdx.x;
    int t = threadIdx.x;
    int node0 = b << BSHIFT;
    int nn = min(1 << BSHIFT, N - node0);
    cnt[t] = 0;
    cnt[t + 256] = 0;
    __syncthreads();
    int sbeg = base[b], send = base[b + 1];
    for (int i = sbeg + t; i < send; i += 256) {
        atomicAdd(&cnt[staging[i] >> 17], 1);
    }
    __syncthreads();
    int c0 = cnt[2 * t], c1 = cnt[2 * t + 1];
    sm[t] = c0 + c1;
    __syncthreads();
    for (int off = 1; off < 256; off <<= 1) {
        int v = (t >= off) ? sm[t - off] : 0;
        __syncthreads();
        sm[t] += v;
        __syncthreads();
    }
    int excl = sm[t] - c0 - c1;
    lrp[2 * t] = excl;
    lrp[2 * t + 1] = excl + c0;
    __syncthreads();
    for (int i = t; i < nn; i += 256) {
        row_ptr[node0 + i] = sbeg + lrp[i];
        int dd = cnt[i];
        inv_deg[node0 + i] = dd > 0 ? 1.0f / (float)dd : 0.0f;
    }
    __syncthreads();
    for (int i = sbeg + t; i < send; i += 256) {
        int word = staging[i];
        int ld = word >> 17;
        int k = atomicSub(&cnt[ld], 1) - 1;
        col[sbeg + lrp[ld] + k] = word & 0x1FFFF;
    }
}

// ---------------- weight prep: f32 -> bf16, transposed ----------------
__global__ __launch_bounds__(256) void prep_w(const float* __restrict__ wl,
                                              const float* __restrict__ wr,
                                              const float* __restrict__ wres,
                                              const float* __restrict__ wfc,
                                              u16* __restrict__ WtL,
                                              u16* __restrict__ WresT,
                                              u16* __restrict__ WfcT) {
    int gid = blockIdx.x * 256 + threadIdx.x;
    int gstr = gridDim.x * 256;
    for (int idx = gid; idx < 3 * 64 * 128; idx += gstr) {
        int l = idx >> 13;
        int rem = idx & 8191;
        int n = rem >> 7;
        int k = rem & 127;
        float v = (k < 64) ? wl[l * 4096 + k * 64 + n] : wr[l * 4096 + (k - 64) * 64 + n];
        WtL[idx] = f2b(v);
    }
    for (int idx = gid; idx < 4096; idx += gstr) {
        int n = idx >> 6, k = idx & 63;
        WresT[idx] = f2b(wres[k * 64 + n]);
        WfcT[idx] = f2b(wfc[k * 64 + n]);
    }
}

// ---------------- f32 -> bf16 mirror ----------------
__global__ __launch_bounds__(256) void cvt_kernel(const float* __restrict__ xf,
                                                  u16* __restrict__ xb, int total4) {
    int i = blockIdx.x * 256 + threadIdx.x;
    int stride = gridDim.x * 256;
    for (; i < total4; i += stride) {
        float4 v = *(const float4*)(xf + i * 4);
        ushort4 o;
        o.x = f2b(v.x); o.y = f2b(v.y); o.z = f2b(v.z); o.w = f2b(v.w);
        *(ushort4*)(xb + i * 4) = o;
    }
}

// ---------------- fused SAGE layer: gather-mean + GEMM + LN + ReLU + residual ----------
// Block = 64-node tile. Stage 1: slot-per-node edge gather -> agg in sA[.,0:64];
// x rows -> sA[.,64:128]. Stage 2: MFMA h = [agg|x]@[Wl;Wr], LN, ReLU, +residual.
// Residual: layer0 = x@w_res+b_res (MFMA, W from global); else bf16 x from sA.
__global__ __launch_bounds__(256, 4) void layer_kernel(const u16* __restrict__ xb_in,
                                                       const int* __restrict__ row_ptr,
                                                       const int* __restrict__ col,
                                                       const float* __restrict__ inv_deg,
                                                       const u16* __restrict__ Wt,    // [64][128]
                                                       const float* __restrict__ bl,
                                                       const float* __restrict__ gam,
                                                       const float* __restrict__ bet,
                                                       const u16* __restrict__ WresT, // [64][64]
                                                       const float* __restrict__ bres,
                                                       u16* __restrict__ xb_out,
                                                       int N, int layer0) {
    __shared__ __align__(16) u16 sA[64 * LPITCH];
    __shared__ __align__(16) u16 sB[64 * LPITCH];
    int tid = threadIdx.x;
    int base = blockIdx.x * 64;
    int lane = tid & 63;
    int w = tid >> 6;

    // stage B (W^T rows), 4 uint4 per thread
#pragma unroll
    for (int i = 0; i < 4; i++) {
        int idx = i * 256 + tid;
        int r = idx >> 4, c = idx & 15;
        *(uint4*)&sB[r * LPITCH + c * 8] = *(const uint4*)(Wt + idx * 8);
    }
    // stage x rows into sA cols 64..127, 2 uint4 per thread
#pragma unroll
    for (int i = 0; i < 2; i++) {
        int idx = i * 256 + tid;
        int r = idx >> 3, c = idx & 7;
        int node = base + r;
        uint4 v = make_uint4(0, 0, 0, 0);
        if (node < N) v = *(const uint4*)(xb_in + node * D + c * 8);
        *(uint4*)&sA[r * LPITCH + 64 + c * 8] = v;
    }

    // gather stage: slot-per-node, 2 rounds x 8 slots per wave = 16 nodes/wave
    int slot = lane >> 3;
    int chunk = lane & 7;
#pragma unroll
    for (int r = 0; r < 2; r++) {
        int node_l = w * 16 + r * 8 + slot;
        int node = base + node_l;
        float a0 = 0, a1 = 0, a2 = 0, a3 = 0, a4 = 0, a5 = 0, a6 = 0, a7 = 0;
        uint4 o = make_uint4(0, 0, 0, 0);
        if (node < N) {
            int e = row_ptr[node], end = row_ptr[node + 1];
#define ACC(v)                                          \
    a0 += u2f_lo(v.x); a1 += u2f_hi(v.x);               \
    a2 += u2f_lo(v.y); a3 += u2f_hi(v.y);               \
    a4 += u2f_lo(v.z); a5 += u2f_hi(v.z);               \
    a6 += u2f_lo(v.w); a7 += u2f_hi(v.w);
            for (; e + 3 < end; e += 4) {       // 4 gathers in flight per slot
                int s0 = col[e], s1 = col[e + 1], s2 = col[e + 2], s3 = col[e + 3];
                uint4 v0 = *(const uint4*)(xb_in + s0 * D + chunk * 8);
                uint4 v1 = *(const uint4*)(xb_in + s1 * D + chunk * 8);
                uint4 v2 = *(const uint4*)(xb_in + s2 * D + chunk * 8);
                uint4 v3 = *(const uint4*)(xb_in + s3 * D + chunk * 8);
                ACC(v0) ACC(v1) ACC(v2) ACC(v3)
            }
            if (e + 1 < end) {
                int s0 = col[e], s1 = col[e + 1];
                uint4 v0 = *(const uint4*)(xb_in + s0 * D + chunk * 8);
                uint4 v1 = *(const uint4*)(xb_in + s1 * D + chunk * 8);
                ACC(v0) ACC(v1)
                e += 2;
            }
            if (e < end) {
                int s0 = col[e];
                uint4 v0 = *(const uint4*)(xb_in + s0 * D + chunk * 8);
                ACC(v0)
            }
#undef ACC
            float m = inv_deg[node];
            o.x = (unsigned)f2b(a0 * m) | ((unsigned)f2b(a1 * m) << 16);
            o.y = (unsigned)f2b(a2 * m) | ((unsigned)f2b(a3 * m) << 16);
            o.z = (unsigned)f2b(a4 * m) | ((unsigned)f2b(a5 * m) << 16);
            o.w = (unsigned)f2b(a6 * m) | ((unsigned)f2b(a7 * m) << 16);
        }
        *(uint4*)&sA[node_l * LPITCH + chunk * 8] = o;
    }
    __syncthreads();

    // GEMM stage
    int q = lane >> 4;
    int ln = lane & 15;
    f32x4 acc[4] = {{0, 0, 0, 0}, {0, 0, 0, 0}, {0, 0, 0, 0}, {0, 0, 0, 0}};
    f32x4 accr[4] = {{0, 0, 0, 0}, {0, 0, 0, 0}, {0, 0, 0, 0}, {0, 0, 0, 0}};
    const u16* aRow = &sA[(w * 16 + ln) * LPITCH];

#pragma unroll
    for (int c = 0; c < 4; c++) {       // K = 128
        bf16x8 a = ld_frag(&aRow[c * 32 + q * 8]);
#pragma unroll
        for (int t = 0; t < 4; t++) {
            bf16x8 b = ld_frag(&sB[(t * 16 + ln) * LPITCH + c * 32 + q * 8]);
            acc[t] = __builtin_amdgcn_mfma_f32_16x16x32_bf16(a, b, acc[t], 0, 0, 0);
        }
    }
    if (layer0) {                       // residual = x @ w_res (B frags from L2-hot global)
#pragma unroll
        for (int c = 0; c < 2; c++) {
            bf16x8 a = ld_frag(&aRow[64 + c * 32 + q * 8]);
#pragma unroll
            for (int t = 0; t < 4; t++) {
                bf16x8 b = ld_frag(WresT + (t * 16 + ln) * 64 + c * 32 + q * 8);
                accr[t] = __builtin_amdgcn_mfma_f32_16x16x32_bf16(a, b, accr[t], 0, 0, 0);
            }
        }
    }

    float bcol[4], gcol[4], btcol[4], brcol[4];
#pragma unroll
    for (int t = 0; t < 4; t++) {
        int colI = t * 16 + ln;
        bcol[t] = bl[colI];
        gcol[t] = gam[colI];
        btcol[t] = bet[colI];
        brcol[t] = layer0 ? bres[colI] : 0.f;
    }
#pragma unroll
    for (int t = 0; t < 4; t++)
#pragma unroll
        for (int r = 0; r < 4; r++) acc[t][r] += bcol[t];

    float ps[4], pq[4];
#pragma unroll
    for (int r = 0; r < 4; r++) {
        float s = 0, s2 = 0;
#pragma unroll
        for (int t = 0; t < 4; t++) { float h = acc[t][r]; s += h; s2 += h * h; }
        ps[r] = s; pq[r] = s2;
    }
    for (int off = 1; off < 16; off <<= 1) {
#pragma unroll
        for (int r = 0; r < 4; r++) {
            ps[r] += __shfl_xor(ps[r], off, 64);
            pq[r] += __shfl_xor(pq[r], off, 64);
        }
    }
#pragma unroll
    for (int r = 0; r < 4; r++) {
        int nb = w * 16 + q * 4 + r;
        int node = base + nb;
        if (node >= N) continue;
        float mu = ps[r] * (1.f / 64.f);
        float var = pq[r] * (1.f / 64.f) - mu * mu;
        var = var < 0.f ? 0.f : var;
        float rstd = rsqrtf(var + 1e-5f);
#pragma unroll
        for (int t = 0; t < 4; t++) {
            int colI = t * 16 + ln;
            float hn = (acc[t][r] - mu) * rstd * gcol[t] + btcol[t];
            hn = hn > 0.f ? hn : 0.f;
            float res = layer0 ? (accr[t][r] + brcol[t])
                               : b2f(sA[nb * LPITCH + 64 + colI]);
            xb_out[node * D + colI] = f2b(hn + res);
        }
    }
}

// ---------------- final fc: out(f32) = x @ w_fc + b_fc ----------------
__global__ __launch_bounds__(256) void fc_kernel(const u16* __restrict__ xbin,
                                                 const u16* __restrict__ WfcT,
                                                 const float* __restrict__ bfc,
                                                 float* __restrict__ out, int N) {
    __shared__ __align__(16) u16 sA[64 * SPITCH];
    __shared__ __align__(16) u16 sB[64 * SPITCH];
    int tid = threadIdx.x;
    int base = blockIdx.x * 64;
#pragma unroll
    for (int i = 0; i < 2; i++) {
        int idx = i * 256 + tid;
        int r = idx >> 3, c = idx & 7;
        int node = base + r;
        uint4 v = make_uint4(0, 0, 0, 0);
        if (node < N) v = *(const uint4*)(xbin + node * D + c * 8);
        *(uint4*)&sA[r * SPITCH + c * 8] = v;
        *(uint4*)&sB[r * SPITCH + c * 8] = *(const uint4*)(WfcT + idx * 8);
    }
    __syncthreads();
    int lane = tid & 63;
    int w = tid >> 6, q = lane >> 4, ln = lane & 15;
    f32x4 acc[4] = {{0, 0, 0, 0}, {0, 0, 0, 0}, {0, 0, 0, 0}, {0, 0, 0, 0}};
#pragma unroll
    for (int c = 0; c < 2; c++) {
        bf16x8 a = ld_frag(&sA[(w * 16 + ln) * SPITCH + c * 32 + q * 8]);
#pragma unroll
        for (int t = 0; t < 4; t++) {
            bf16x8 b = ld_frag(&sB[(t * 16 + ln) * SPITCH + c * 32 + q * 8]);
            acc[t] = __builtin_amdgcn_mfma_f32_16x16x32_bf16(a, b, acc[t], 0, 0, 0);
        }
    }
#pragma unroll
    for (int r = 0; r < 4; r++) {
        int node = base + w * 16 + q * 4 + r;
        if (node >= N) continue;
#pragma unroll
        for (int t = 0; t < 4; t++) {
            int colI = t * 16 + ln;
            out[node * D + colI] = acc[t][r] + bfc[colI];
        }
    }
}

extern "C" void kernel_launch(void* const* d_in, const int* in_sizes, int n_in,
                              void* d_out, int out_size, void* d_ws, size_t ws_size,
                              hipStream_t stream) {
    const float* x_in = (const float*)d_in[0];
    const int* e_src = (const int*)d_in[1];
    const int* e_dst = (const int*)d_in[2];
    const float* w_l = (const float*)d_in[3];
    const float* b_l = (const float*)d_in[4];
    const float* w_r = (const float*)d_in[5];
    const float* gam = (const float*)d_in[6];
    const float* bet = (const float*)d_in[7];
    const float* w_res = (const float*)d_in[8];
    const float* b_res = (const float*)d_in[9];
    const float* w_fc = (const float*)d_in[10];
    const float* b_fc = (const float*)d_in[11];
    float* out = (float*)d_out;

    const int N = in_sizes[0] / D;
    const int E = in_sizes[1];
    const int nbuck = ((N - 1) >> BSHIFT) + 1;
    const int eper = (E + CHUNKS - 1) / CHUNKS;

    size_t o = 0;
    auto carve = [&](size_t bytes) {
        size_t cur = o;
        o += (bytes + 255) & ~(size_t)255;
        return (char*)d_ws + cur;
    };
    int* row_ptr = (int*)carve((size_t)(N + 1) * 4);
    float* inv_deg = (float*)carve((size_t)N * 4);
    int* colA = (int*)carve((size_t)E * 4);
    int* staging = (int*)carve((size_t)E * 4);
    int* Hh = (int*)carve((size_t)CHUNKS * nbuck * 4);
    int* Orel = (int*)carve((size_t)CHUNKS * nbuck * 4);
    int* Tb = (int*)carve((size_t)nbuck * 4);
    int* baseB = (int*)carve((size_t)(nbuck + 1) * 4);
    u16* WtL = (u16*)carve(3 * 64 * 128 * 2);
    u16* WresT = (u16*)carve(64 * 64 * 2);
    u16* WfcT = (u16*)carve(64 * 64 * 2);
    u16* xbA = (u16*)carve((size_t)N * D * 2);
    u16* xbB = (u16*)carve((size_t)N * D * 2);

    // CSR build (binned, LDS-atomics only)
    binA_kernel<<<CHUNKS, 256, 0, stream>>>(e_dst, E, Hh, nbuck, eper);
    binS2_kernel<<<nbuck, 256, 0, stream>>>(Hh, Orel, Tb, nbuck);
    binT_kernel<<<1, 256, 0, stream>>>(Tb, nbuck, baseB, row_ptr, N);
    binB_kernel<<<CHUNKS, 256, 0, stream>>>(e_src, e_dst, E, baseB, Orel, staging, nbuck, eper);
    binC_kernel<<<nbuck, 256, 0, stream>>>(staging, baseB, row_ptr, inv_deg, colA, N);

    prep_w<<<32, 256, 0, stream>>>(w_l, w_r, w_res, w_fc, WtL, WresT, WfcT);
    cvt_kernel<<<1024, 256, 0, stream>>>(x_in, xbA, N * D / 4);

    int gridT = (N + 63) / 64;

    // layer 0: xbA -> xbB  (residual via w_res MFMA)
    layer_kernel<<<gridT, 256, 0, stream>>>(xbA, row_ptr, colA, inv_deg, WtL,
                                            b_l, gam, bet, WresT, b_res, xbB, N, 1);
    // layer 1: xbB -> xbA
    layer_kernel<<<gridT, 256, 0, stream>>>(xbB, row_ptr, colA, inv_deg, WtL + 8192,
                                            b_l + 64, gam + 64, bet + 64, WresT, b_res,
                                            xbA, N, 0);
    // layer 2: xbA -> xbB
    layer_kernel<<<gridT, 256, 0, stream>>>(xbA, row_ptr, colA, inv_deg, WtL + 16384,
                                            b_l + 128, gam + 128, bet + 128, WresT, b_res,
                                            xbB, N, 0);
    // final fc: xbB -> out
    fc_kernel<<<gridT, 256, 0, stream>>>(xbB, WfcT, b_fc, out, N);
}